// Round 10
// baseline (529.550 us; speedup 1.0000x reference)
//
#include <hip/hip_runtime.h>
#include <hip/hip_bf16.h>
#include <math.h>
#include <stdint.h>

// ---------------------------------------------------------------------------
// Full U-Mamba block. R19: scan_k exp-pipelining (latency fix).
//   R18 counters: scan_k VALUBusy 54%, VGPR 44 -> allocator packed to the
//   minimum; no cross-iteration scheduling. Per-l chain load dt -> v_exp
//   (trans latency) -> dependent fma serializes; ~46% of cycles are stalls.
//   R19: 2-deep load prefetch + exp computed ONE ITERATION AHEAD (e[] cur,
//   en[] next). Trans pipe (en) overlaps VALU pipe (h-updates); the h-chain
//   no longer has a trans op in its dependency path.
// R17/R18 wins kept: HW exp2 in scan, HW softplus in dbc.
// ---------------------------------------------------------------------------

typedef __attribute__((ext_vector_type(8))) short short8;   // 8 bf16 = 4 VGPR
typedef __attribute__((ext_vector_type(4))) float f32x4;

__device__ __forceinline__ float siluf(float x){ return x * (1.0f / (1.0f + __expf(-x))); }
__device__ __forceinline__ float softplusf(float x){ return fmaxf(x, 0.0f) + log1pf(__expf(-fabsf(x))); }
// HW-transcendental softplus: v_exp_f32 + v_log_f32 (both ~1ulp), ~6 VALU ops.
__device__ __forceinline__ float softplus_hw(float x){
  float t = __builtin_amdgcn_exp2f(-fabsf(x) * 1.44269504088896f);
  return fmaxf(x, 0.0f) + 0.69314718055995f * __builtin_amdgcn_logf(1.0f + t);
}
__device__ __forceinline__ float b2f(short s){
  unsigned int u = ((unsigned int)(unsigned short)s) << 16;
  float f; __builtin_memcpy(&f, &u, 4); return f;
}
__device__ __forceinline__ short f2b(float v){
  __hip_bfloat16 h = __float2bfloat16(v);
  unsigned short u; __builtin_memcpy(&u, &h, 2); return (short)u;
}

// async global->LDS, 16B per lane; LDS dest is wave-uniform base + lane*16.
__device__ __forceinline__ void gld_lds16(const void* g, void* l){
  __builtin_amdgcn_global_load_lds(
      (__attribute__((address_space(1))) void*)(uintptr_t)g,
      (__attribute__((address_space(3))) void*)(uint32_t)(uintptr_t)l,
      16, 0, 0);
}

// ---------------------------------------------------------------------------
// One-shot setup: zero xpad | pack conv weights a/b -> bf16 [tap][co][ci] |
// mamba weight bf16 tables | negA2[s] = -softplus(A_log[s]) * log2(e).
// ---------------------------------------------------------------------------
__global__ __launch_bounds__(256) void setup_k(uint4* __restrict__ xz,
    const float* __restrict__ cr1w, const float* __restrict__ cr2w,
    const float* __restrict__ lw, const float* __restrict__ rwt,
    const float* __restrict__ dwt, const float* __restrict__ bw,
    const float* __restrict__ cwp, const float* __restrict__ owt,
    const float* __restrict__ alog,
    __hip_bfloat16* __restrict__ W4a, __hip_bfloat16* __restrict__ W4b,
    __hip_bfloat16* __restrict__ Wlr, __hip_bfloat16* __restrict__ Wd,
    __hip_bfloat16* __restrict__ oWp, float* __restrict__ negA2)
{
  int i = blockIdx.x * 256 + threadIdx.x;
  if (i < 628864){ uint4 z; z.x = z.y = z.z = z.w = 0u; xz[i] = z; return; }
  i -= 628864;
  if (i < 110592){
    int tap = i >> 12, co = (i >> 6) & 63, ci = i & 63;
    W4a[i] = __float2bfloat16(cr1w[(co * 64 + ci) * 27 + tap]); return;
  }
  i -= 110592;
  if (i < 110592){
    int tap = i >> 12, co = (i >> 6) & 63, ci = i & 63;
    W4b[i] = __float2bfloat16(cr2w[(co * 64 + ci) * 27 + tap]); return;
  }
  i -= 110592;
  if (i < 16384){
    int row = i >> 6, c = i & 63;
    float v = (row < 128) ? lw[row * 64 + c] : rwt[(row - 128) * 64 + c];
    Wlr[i] = __float2bfloat16(v); return;
  }
  i -= 16384;
  if (i < 20480){
    int row = i >> 7, k = i & 127;
    float v = (row < 128) ? dwt[row * 128 + k]
            : (row < 144 ? bw[(row - 128) * 128 + k] : cwp[(row - 144) * 128 + k]);
    Wd[i] = __float2bfloat16(v); return;
  }
  i -= 20480;
  if (i < 8192){ oWp[i] = __float2bfloat16(owt[i]); return; }
  i -= 8192;
  if (i < 16){ negA2[i] = -softplusf(alog[i]) * 1.44269504088896f; return; }
}

// ---------------------------------------------------------------------------
// Pack fp32 NCDHW -> padded channels-last bf16 [b][h+1][w+1][d+1][c] (conv1).
// ---------------------------------------------------------------------------
__global__ __launch_bounds__(256) void pack_k(const float* __restrict__ xin,
                                              __hip_bfloat16* __restrict__ xpad)
{
  __shared__ float lds[64 * 33];
  const int t = threadIdx.x, blk = blockIdx.x;
  const int b = blk >> 10, h = (blk >> 5) & 31, w = blk & 31;
  const size_t rbase = ((size_t)(b * 64) << 15) + h * 1024 + w * 32;
  #pragma unroll
  for (int r = 0; r < 8; r++){
    int c = r * 8 + (t >> 5), d = t & 31;
    lds[c * 33 + d] = xin[rbase + (size_t)c * 32768 + d];
  }
  __syncthreads();
  const size_t wbase = (size_t)b * 2515456 + (size_t)(h + 1) * 73984 + (w + 1) * 2176 + 64;
  #pragma unroll
  for (int r = 0; r < 8; r++){
    int d = r * 4 + (t >> 6), c = t & 63;
    xpad[wbase + d * 64 + c] = __float2bfloat16(lds[c * 33 + d]);
  }
}

// ---------------------------------------------------------------------------
// Conv3d implicit GEMM, bf16 MFMA 16x16x32, LDS-staged (m97 pattern, R8).
// ---------------------------------------------------------------------------
__global__ __launch_bounds__(256) void conv_mfma_k(const __hip_bfloat16* __restrict__ xpad,
    const __hip_bfloat16* __restrict__ W4, float* __restrict__ y)
{
  __shared__ short smem[6144];   // [0,4096): B tile; [4096,6144): A tile

  const int t = threadIdx.x;
  const int wave = t >> 6, lane = t & 63;
  const int quad = lane >> 4, ln = lane & 15;

  const int blk = blockIdx.x;          // 512 blocks
  const int xcd = blk & 7, j = blk >> 3;
  const int b = j >> 5, jj = j & 31;
  const int h = xcd * 4 + (jj >> 3);
  const int w0 = (jj & 7) * 4;

  const int bcol = (lane >> 2) * 64 + (lane & 3) * 8;
  const __hip_bfloat16* Bg = xpad + (size_t)b * 2515456 + (size_t)h * 73984
                                  + (size_t)(w0 + wave) * 2176 + bcol;
  const __hip_bfloat16* Ag = W4 + wave * 1024 + bcol;
  short* Bl0 = &smem[wave * 1024];
  short* Bl1 = &smem[wave * 1024 + 512];
  short* Al  = &smem[4096 + wave * 512];

  f32x4 acc[2][4];
  #pragma unroll
  for (int jn = 0; jn < 2; jn++)
    #pragma unroll
    for (int m = 0; m < 4; m++) acc[jn][m] = (f32x4){0.f, 0.f, 0.f, 0.f};

  const int aoff = ln * 32 + quad * 8;
  const int boff = (wave * 32 + ln) * 32 + quad * 8;

  for (int s = 0; s < 54; s++){
    const int t1 = s >> 1, ch = s & 1;
    const int ki = t1 / 9, kj = (t1 / 3) % 3, kk = t1 % 3;
    const int tapoff = ki * 73984 + kj * 2176 + kk * 64 + ch * 32;

    __syncthreads();
    gld_lds16(Bg + tapoff,        Bl0);
    gld_lds16(Bg + tapoff + 1024, Bl1);
    gld_lds16(Ag + t1 * 4096 + ch * 32, Al);
    __syncthreads();

    short8 a0 = *(const short8*)&smem[4096 + aoff];
    short8 a1 = *(const short8*)&smem[4096 + 512 + aoff];
    short8 a2 = *(const short8*)&smem[4096 + 1024 + aoff];
    short8 a3 = *(const short8*)&smem[4096 + 1536 + aoff];
    short8 b0 = *(const short8*)&smem[boff];
    short8 b1 = *(const short8*)&smem[boff + 512];

    acc[0][0] = __builtin_amdgcn_mfma_f32_16x16x32_bf16(a0, b0, acc[0][0], 0, 0, 0);
    acc[0][1] = __builtin_amdgcn_mfma_f32_16x16x32_bf16(a1, b0, acc[0][1], 0, 0, 0);
    acc[0][2] = __builtin_amdgcn_mfma_f32_16x16x32_bf16(a2, b0, acc[0][2], 0, 0, 0);
    acc[0][3] = __builtin_amdgcn_mfma_f32_16x16x32_bf16(a3, b0, acc[0][3], 0, 0, 0);
    acc[1][0] = __builtin_amdgcn_mfma_f32_16x16x32_bf16(a0, b1, acc[1][0], 0, 0, 0);
    acc[1][1] = __builtin_amdgcn_mfma_f32_16x16x32_bf16(a1, b1, acc[1][1], 0, 0, 0);
    acc[1][2] = __builtin_amdgcn_mfma_f32_16x16x32_bf16(a2, b1, acc[1][2], 0, 0, 0);
    acc[1][3] = __builtin_amdgcn_mfma_f32_16x16x32_bf16(a3, b1, acc[1][3], 0, 0, 0);
  }

  const size_t sbase = (size_t)h * 1024 + (w0 + wave) * 32 + ln;
  #pragma unroll
  for (int jn = 0; jn < 2; jn++){
    #pragma unroll
    for (int mt = 0; mt < 4; mt++){
      #pragma unroll
      for (int reg = 0; reg < 4; reg++){
        int co = mt * 16 + quad * 4 + reg;
        y[(((size_t)(b * 64 + co)) << 15) + sbase + jn * 16] = acc[jn][mt][reg];
      }
    }
  }
}

// ---------------------------------------------------------------------------
// InstanceNorm3d stats: one block per (b,c); stats[g]=mu, stats[128+g]=rsigma.
// ---------------------------------------------------------------------------
__global__ __launch_bounds__(256) void inorm_stats_k(const float* __restrict__ y,
                                                     float* __restrict__ stats)
{
  __shared__ float ss[256], ss2[256];
  const int t = threadIdx.x, g = blockIdx.x;
  const float* p = y + (size_t)g * 32768;
  float s = 0.0f, s2 = 0.0f;
  for (int i = t; i < 32768; i += 256){ float v = p[i]; s += v; s2 += v * v; }
  ss[t] = s; ss2[t] = s2;
  __syncthreads();
  for (int off = 128; off > 0; off >>= 1){
    if (t < off){ ss[t] += ss[t + off]; ss2[t] += ss2[t + off]; }
    __syncthreads();
  }
  if (t == 0){
    float mu = ss[0] * (1.0f / 32768.0f);
    float var = ss2[0] * (1.0f / 32768.0f) - mu * mu;
    stats[g] = mu;
    stats[128 + g] = rsqrtf(var + 1e-5f);
  }
}

// ---------------------------------------------------------------------------
// Fused: InstanceNorm-apply + LeakyReLU + residual -> x1 (fp32 NCDHW)
// AND bf16 channels-last re-pack into xpad (input of conv2).
// ---------------------------------------------------------------------------
__global__ __launch_bounds__(256) void apply_pack_k(const float* __restrict__ xin,
    const float* __restrict__ y, const float* __restrict__ stats,
    float* __restrict__ x1, __hip_bfloat16* __restrict__ xpad)
{
  __shared__ float lds[64 * 33];
  const int t = threadIdx.x, blk = blockIdx.x;
  const int b = blk >> 10, h = (blk >> 5) & 31, w = blk & 31;
  const size_t rbase = ((size_t)(b * 64) << 15) + h * 1024 + w * 32;
  #pragma unroll
  for (int r = 0; r < 8; r++){
    int c = r * 8 + (t >> 5), d = t & 31;
    float mu = stats[b * 64 + c], rs = stats[128 + b * 64 + c];
    float v = (y[rbase + (size_t)c * 32768 + d] - mu) * rs;
    v = (v >= 0.0f) ? v : 0.01f * v;
    v += xin[rbase + (size_t)c * 32768 + d];
    x1[rbase + (size_t)c * 32768 + d] = v;
    lds[c * 33 + d] = v;
  }
  __syncthreads();
  const size_t wbase = (size_t)b * 2515456 + (size_t)(h + 1) * 73984 + (w + 1) * 2176 + 64;
  #pragma unroll
  for (int r = 0; r < 8; r++){
    int d = r * 4 + (t >> 6), c = t & 63;
    xpad[wbase + d * 64 + c] = __float2bfloat16(lds[c * 33 + d]);
  }
}

// ---------------------------------------------------------------------------
// Fused: InstanceNorm-apply + LeakyReLU + residual + LayerNorm over C
// -> bf16 channels-last lnx [pos][64]. x2 never materialized.
// ---------------------------------------------------------------------------
__global__ __launch_bounds__(256) void apply_ln_k(const float* __restrict__ x1,
    const float* __restrict__ y, const float* __restrict__ stats,
    const float* __restrict__ lnw, const float* __restrict__ lnb,
    __hip_bfloat16* __restrict__ lnx)
{
  __shared__ float lds[64 * 33];
  __shared__ float s_mu[32], s_rs[32];
  const int t = threadIdx.x, blk = blockIdx.x;
  const int b = blk >> 10, h = (blk >> 5) & 31, w = blk & 31;
  const size_t rbase = ((size_t)(b * 64) << 15) + h * 1024 + w * 32;
  #pragma unroll
  for (int r = 0; r < 8; r++){
    int c = r * 8 + (t >> 5), d = t & 31;
    float mu = stats[b * 64 + c], rs = stats[128 + b * 64 + c];
    float v = (y[rbase + (size_t)c * 32768 + d] - mu) * rs;
    v = (v >= 0.0f) ? v : 0.01f * v;
    lds[c * 33 + d] = v + x1[rbase + (size_t)c * 32768 + d];
  }
  __syncthreads();
  if (t < 32){
    float s = 0.f, s2 = 0.f;
    for (int c = 0; c < 64; c++){ float v = lds[c * 33 + t]; s += v; s2 += v * v; }
    float mu = s * (1.f / 64.f);
    float var = s2 * (1.f / 64.f) - mu * mu;
    s_mu[t] = mu; s_rs[t] = rsqrtf(var + 1e-5f);
  }
  __syncthreads();
  const int d = t >> 3, c0 = (t & 7) * 8;
  const int pos = b * 32768 + h * 1024 + w * 32 + d;
  const float mu = s_mu[d], rs = s_rs[d];
  short8 o;
  #pragma unroll
  for (int j = 0; j < 8; j++){
    int c = c0 + j;
    o[j] = f2b((lds[c * 33 + d] - mu) * rs * lnw[c] + lnb[c]);
  }
  *(short8*)&lnx[(size_t)pos * 64 + c0] = o;
}

// ---------------------------------------------------------------------------
// GEMM [65536,64] x [64,256] -> Lbuf (cols 0-127 raw) + Gbuf (silu, 128-255).
// ---------------------------------------------------------------------------
__global__ __launch_bounds__(256) void gemm_lr_k(const __hip_bfloat16* __restrict__ lnx,
    const __hip_bfloat16* __restrict__ Wlr, __hip_bfloat16* __restrict__ Lb,
    __hip_bfloat16* __restrict__ Gb)
{
  const int t = threadIdx.x, wave = t >> 6, lane = t & 63, quad = lane >> 4, ln = lane & 15;
  const int pos0 = blockIdx.x * 64 + wave * 16;
  f32x4 acc[16];
  #pragma unroll
  for (int nt = 0; nt < 16; nt++) acc[nt] = (f32x4){0.f, 0.f, 0.f, 0.f};
  #pragma unroll
  for (int ks = 0; ks < 2; ks++){
    short8 a = *(const short8*)&lnx[(size_t)(pos0 + ln) * 64 + ks * 32 + quad * 8];
    #pragma unroll
    for (int nt = 0; nt < 16; nt++){
      short8 bv = *(const short8*)&Wlr[(nt * 16 + ln) * 64 + ks * 32 + quad * 8];
      acc[nt] = __builtin_amdgcn_mfma_f32_16x16x32_bf16(a, bv, acc[nt], 0, 0, 0);
    }
  }
  #pragma unroll
  for (int nt = 0; nt < 16; nt++){
    int col = nt * 16 + ln;
    #pragma unroll
    for (int reg = 0; reg < 4; reg++){
      int pos = pos0 + quad * 4 + reg;
      float v = acc[nt][reg];
      if (col < 128) Lb[(size_t)pos * 128 + col] = __float2bfloat16(v);
      else           Gb[(size_t)pos * 128 + col - 128] = __float2bfloat16(siluf(v));
    }
  }
}

// ---------------------------------------------------------------------------
// FUSED per-axis: conv1d(k=4)+silu -> LDS tile -> GEMM [64,128]x[128,160].
// R18: epilogue softplus via softplus_hw (v_exp+v_log, ~6 ops vs libm ~28).
// ---------------------------------------------------------------------------
__global__ __launch_bounds__(256) void dbc_k(const __hip_bfloat16* __restrict__ Lb,
    const float* __restrict__ cw, const float* __restrict__ cb,
    const __hip_bfloat16* __restrict__ Wd, const float* __restrict__ db,
    __hip_bfloat16* __restrict__ xl, __hip_bfloat16* __restrict__ dbc, int sh)
{
  __shared__ short s_xl[64 * 136];
  const int t = threadIdx.x;
  const int pos0 = blockIdx.x * 64;
  const int sigma = 1 << sh;

  const int c0 = (t & 15) * 8;
  const int pibase = t >> 4;
  float4 w4[8]; float cbv[8];
  #pragma unroll
  for (int c = 0; c < 8; c++){ w4[c] = *(const float4*)&cw[(c0 + c) * 4]; cbv[c] = cb[c0 + c]; }

  #pragma unroll
  for (int r = 0; r < 4; r++){
    int pi = pibase + r * 16;
    int pos = pos0 + pi;
    int l = (pos >> sh) & 31;
    float acc[8];
    #pragma unroll
    for (int c = 0; c < 8; c++) acc[c] = cbv[c];
    #pragma unroll
    for (int j = 0; j < 4; j++){
      int off = 3 - j;
      if (l >= off){
        short8 lv = *(const short8*)&Lb[(size_t)(pos - off * sigma) * 128 + c0];
        #pragma unroll
        for (int c = 0; c < 8; c++){
          float wv = (j == 0) ? w4[c].x : (j == 1) ? w4[c].y : (j == 2) ? w4[c].z : w4[c].w;
          acc[c] += wv * b2f(lv[c]);
        }
      }
    }
    short8 o;
    #pragma unroll
    for (int c = 0; c < 8; c++) o[c] = f2b(siluf(acc[c]));
    *(short8*)&s_xl[pi * 136 + c0] = o;
    *(short8*)&xl[(size_t)pos * 128 + c0] = o;
  }
  __syncthreads();

  const int wave = t >> 6, lane = t & 63, quad = lane >> 4, ln = lane & 15;
  const int rowb = (wave * 16 + ln) * 136;
  f32x4 acc2[10];
  #pragma unroll
  for (int nt = 0; nt < 10; nt++) acc2[nt] = (f32x4){0.f, 0.f, 0.f, 0.f};
  #pragma unroll
  for (int ks = 0; ks < 4; ks++){
    short8 a = *(const short8*)&s_xl[rowb + ks * 32 + quad * 8];
    #pragma unroll
    for (int nt = 0; nt < 10; nt++){
      short8 bv = *(const short8*)&Wd[(nt * 16 + ln) * 128 + ks * 32 + quad * 8];
      acc2[nt] = __builtin_amdgcn_mfma_f32_16x16x32_bf16(a, bv, acc2[nt], 0, 0, 0);
    }
  }
  const int posw = pos0 + wave * 16 + quad * 4;
  #pragma unroll
  for (int nt = 0; nt < 10; nt++){
    int col = nt * 16 + ln;
    bool isd = col < 128;
    float dbv = isd ? db[col] : 0.f;
    #pragma unroll
    for (int reg = 0; reg < 4; reg++){
      float v = acc2[nt][reg];
      if (isd) v = fminf(fmaxf(softplus_hw(v + dbv), 1e-4f), 10.f);
      dbc[(size_t)(posw + reg) * 160 + col] = __float2bfloat16(v);
    }
  }
}

// ---------------------------------------------------------------------------
// Per-axis selective scan + gate + post-LN + wax-weighted ACCUMULATE into
// Yacc (bf16, pos-major).
// R19: 2-deep load prefetch; exp2 for iteration l+1 computed during l
//   (e[] current / en[] next). Trans pipe overlaps VALU; h-chain has no
//   trans op in its dependency path.
// ---------------------------------------------------------------------------
__global__ __launch_bounds__(256) void scan_k(const __hip_bfloat16* __restrict__ dbc,
    const __hip_bfloat16* __restrict__ xl, const __hip_bfloat16* __restrict__ Gb,
    const float* __restrict__ negA2, const float* __restrict__ pnw,
    const float* __restrict__ pnb, const float* __restrict__ axw,
    __hip_bfloat16* __restrict__ Yacc, int axis, int first)
{
  __shared__ float s_B[2][32][16];           // [seq_local][l][state]
  __shared__ float s_C[2][32][16];
  __shared__ unsigned short s_y[2][32][132]; // gated y, bf16; row pad -> 264B
  __shared__ float s_stat[2][32][2];         // per-l {sum, sumsq} over 128 ch

  const int t = threadIdx.x;
  const int wv = t >> 6, lane = t & 63;
  const int sl = wv >> 1;                    // seq_local 0/1
  const int half = wv & 1;                   // channel half 0/1
  const int seq = blockIdx.x * 2 + sl;
  const int b = seq >> 10, r1 = (seq >> 5) & 31, r0 = seq & 31;
  int base, sigma;
  if (axis == 0){      base = b * 32768 + r1 * 32 + r0;        sigma = 1024; }
  else if (axis == 1){ base = b * 32768 + r1 * 1024 + r0;      sigma = 32; }
  else {               base = b * 32768 + r1 * 1024 + r0 * 32; sigma = 1; }

  // --- cooperative B/C staging: 256 threads cover 2 seqs x 32 l x 32 bf16 ---
  {
    const int row = t >> 2, sub = t & 3;     // row 0..63 = seq_local*32 + l
    const int seq_s = blockIdx.x * 2 + (row >> 5);
    const int bs = seq_s >> 10, r1s = (seq_s >> 5) & 31, r0s = seq_s & 31;
    int base_s;
    if (axis == 0)      base_s = bs * 32768 + r1s * 32 + r0s;
    else if (axis == 1) base_s = bs * 32768 + r1s * 1024 + r0s;
    else                base_s = bs * 32768 + r1s * 1024 + r0s * 32;
    const int ls = row & 31;
    const int pos = base_s + ls * sigma;
    short8 v = *(const short8*)&dbc[(size_t)pos * 160 + 128 + sub * 8];
    float* dst = (sub < 2) ? &s_B[row >> 5][ls][(sub & 1) * 8]
                           : &s_C[row >> 5][ls][(sub & 1) * 8];
    #pragma unroll
    for (int j = 0; j < 8; j++) dst[j] = b2f(v[j]);
  }

  float A2[16], h[16];
  #pragma unroll
  for (int s = 0; s < 16; s++){ A2[s] = negA2[s]; h[s] = 0.f; }

  const int ch = half * 64 + lane;
  __syncthreads();

  const __hip_bfloat16* pd = dbc + (size_t)base * 160 + ch;
  const __hip_bfloat16* px = xl  + (size_t)base * 128 + ch;
  const __hip_bfloat16* pg = Gb  + (size_t)base * 128 + ch;
  const size_t sd = (size_t)sigma * 160;
  const size_t sx = (size_t)sigma * 128;

  // --- Phase 1: serial scan, 2-deep prefetch + 1-ahead exp pipeline ------
  // du/xu/gu: current l.  ndu/nxu/ngu: l+1 (loaded 1 iter ago).
  // e[]: exps for current l (computed 1 iter ago from the prefetched dt).
  unsigned short du, xu, gu, ndu, nxu, ngu;
  du  = *(const unsigned short*)pd;
  xu  = *(const unsigned short*)px;
  gu  = *(const unsigned short*)pg;
  ndu = *(const unsigned short*)(pd + sd);
  nxu = *(const unsigned short*)(px + sx);
  ngu = *(const unsigned short*)(pg + sx);

  float e[16];
  {
    const float dt0 = b2f((short)du);
    #pragma unroll
    for (int s = 0; s < 16; s++) e[s] = __builtin_amdgcn_exp2f(dt0 * A2[s]);
  }

  #pragma unroll
  for (int l = 0; l < 32; l++){
    unsigned short n2du = 0, n2xu = 0, n2gu = 0;
    if (l + 2 < 32){
      n2du = *(const unsigned short*)(pd + 2 * sd);
      n2xu = *(const unsigned short*)(px + 2 * sx);
      n2gu = *(const unsigned short*)(pg + 2 * sx);
    }
    // exps for l+1 (trans pipe) — independent of this iteration's h-chain
    float en[16];
    {
      const float dtn = b2f((short)ndu);
      #pragma unroll
      for (int s = 0; s < 16; s++) en[s] = __builtin_amdgcn_exp2f(dtn * A2[s]);
    }
    float dt = b2f((short)du), xt = b2f((short)xu), g = b2f((short)gu);
    float dx = dt * xt;
    f32x4 Bq[4], Cq[4];
    #pragma unroll
    for (int q = 0; q < 4; q++){
      Bq[q] = *(const f32x4*)&s_B[sl][l][q * 4];
      Cq[q] = *(const f32x4*)&s_C[sl][l][q * 4];
    }
    float y = 0.f;
    #pragma unroll
    for (int q = 0; q < 4; q++){
      #pragma unroll
      for (int r = 0; r < 4; r++){
        const int s = q * 4 + r;
        h[s] = e[s] * h[s] + dx * Bq[q][r];
        y += h[s] * Cq[q][r];
      }
    }
    s_y[sl][l][ch] = (unsigned short)f2b(y * g);
    du = ndu; xu = nxu; gu = ngu;
    ndu = n2du; nxu = n2xu; ngu = n2gu;
    #pragma unroll
    for (int s = 0; s < 16; s++) e[s] = en[s];
    pd += sd; px += sx; pg += sx;
  }
  __syncthreads();

  // --- Phase 2: cooperative per-l reduction (sum, sumsq over 128 ch) -----
  {
    const int row = t >> 2, part = t & 3;    // row = sl2*32 + l2
    const int sl2 = row >> 5, l2 = row & 31;
    const unsigned short* yr = &s_y[sl2][l2][part * 32];
    float s1 = 0.f, s2 = 0.f;
    #pragma unroll
    for (int i = 0; i < 32; i++){
      float v = b2f((short)yr[i]);
      s1 += v; s2 += v * v;
    }
    s1 += __shfl_xor(s1, 1); s2 += __shfl_xor(s2, 1);
    s1 += __shfl_xor(s1, 2); s2 += __shfl_xor(s2, 2);
    if (part == 0){ s_stat[sl2][l2][0] = s1; s_stat[sl2][l2][1] = s2; }
  }
  __syncthreads();

  // --- Phase 3: LN over 128 ch + wax + Yacc accumulate -------------------
  float a0 = axw[0], a1 = axw[1], a2 = axw[2];
  float mxw = fmaxf(a0, fmaxf(a1, a2));
  float e0 = __expf(a0 - mxw), e1 = __expf(a1 - mxw), e2 = __expf(a2 - mxw);
  float wax = ((axis == 0) ? e0 : (axis == 1) ? e1 : e2) / (e0 + e1 + e2);
  const float pw = pnw[ch], pb = pnb[ch];

  __hip_bfloat16* py = Yacc + (size_t)base * 128 + ch;
  #pragma unroll
  for (int l = 0; l < 32; l++){
    float ss1 = s_stat[sl][l][0];
    float ss2 = s_stat[sl][l][1];
    float mu = ss1 * (1.f / 128.f);
    float var = ss2 * (1.f / 128.f) - mu * mu;
    float rs = rsqrtf(fmaxf(var, 0.f) + 1e-5f);
    float yv = b2f((short)s_y[sl][l][ch]);
    float o = ((yv - mu) * rs * pw + pb) * wax;
    if (!first) o += b2f((short)*(const unsigned short*)py);
    *(unsigned short*)py = (unsigned short)f2b(o);
    py += sx;
  }
}

// ---------------------------------------------------------------------------
// SINGLE out-projection GEMM (Yacc already holds sum of wax-weighted Y over
// all 3 axes) + residual finalize: out = x + rs * (Yacc @ oW^T). Coalesced.
// ---------------------------------------------------------------------------
__global__ __launch_bounds__(256) void gemm_out_k(const __hip_bfloat16* __restrict__ Yb,
    const __hip_bfloat16* __restrict__ oW, const float* __restrict__ xres,
    const float* __restrict__ rsc, float* __restrict__ outp)
{
  const int t = threadIdx.x, wave = t >> 6, lane = t & 63, quad = lane >> 4, ln = lane & 15;
  const int pos0 = blockIdx.x * 64 + wave * 16;
  f32x4 acc[4];
  #pragma unroll
  for (int mt = 0; mt < 4; mt++) acc[mt] = (f32x4){0.f, 0.f, 0.f, 0.f};
  #pragma unroll
  for (int ks = 0; ks < 4; ks++){
    short8 bv = *(const short8*)&Yb[(size_t)(pos0 + ln) * 128 + ks * 32 + quad * 8];
    #pragma unroll
    for (int mt = 0; mt < 4; mt++){
      short8 a = *(const short8*)&oW[(mt * 16 + ln) * 128 + ks * 32 + quad * 8];
      acc[mt] = __builtin_amdgcn_mfma_f32_16x16x32_bf16(a, bv, acc[mt], 0, 0, 0);
    }
  }
  float rs = rsc[0];
  const int pos = pos0 + ln;
  const int bb = pos >> 15, hwd = pos & 32767;
  #pragma unroll
  for (int mt = 0; mt < 4; mt++){
    #pragma unroll
    for (int reg = 0; reg < 4; reg++){
      int co = mt * 16 + quad * 4 + reg;
      size_t idx = (((size_t)(bb * 64 + co)) << 15) + hwd;
      outp[idx] = xres[idx] + rs * acc[mt][reg];
    }
  }
}

// ---------------------------------------------------------------------------
extern "C" void kernel_launch(void* const* d_in, const int* in_sizes, int n_in,
                              void* d_out, int out_size, void* d_ws, size_t ws_size,
                              hipStream_t stream)
{
  const float* x      = (const float*)d_in[0];
  const float* cr1w   = (const float*)d_in[1];
  const float* cr2w   = (const float*)d_in[3];
  const float* ln_w   = (const float*)d_in[5];
  const float* ln_b   = (const float*)d_in[6];
  const float* left_w = (const float*)d_in[7];
  const float* c1dw   = (const float*)d_in[8];
  const float* c1db   = (const float*)d_in[9];
  const float* dw     = (const float*)d_in[10];
  const float* db     = (const float*)d_in[11];
  const float* bpw    = (const float*)d_in[12];
  const float* cpw    = (const float*)d_in[13];
  const float* alog   = (const float*)d_in[14];
  const float* rw     = (const float*)d_in[15];
  const float* pnw    = (const float*)d_in[16];
  const float* pnb    = (const float*)d_in[17];
  const float* ow     = (const float*)d_in[18];
  const float* rsc    = (const float*)d_in[19];
  const float* axw    = (const float*)d_in[20];
  float* out = (float*)d_out;                       // conv raw out, then final out
  float* wsf = (float*)d_ws;

  float* buf1   = wsf;                                         // x1 fp32; later xl bf16 alias
  float* stats  = wsf + 4194304;                               // 256 f
  float* negA2  = wsf + 4194560;                               // 16 f
  __hip_bfloat16* W4a  = (__hip_bfloat16*)(wsf + 4194816);     // 110,592 bf16
  __hip_bfloat16* W4b  = W4a + 110592;
  __hip_bfloat16* Wlr  = (__hip_bfloat16*)(wsf + 4305408);     // 16,384 bf16
  __hip_bfloat16* Wdbc = (__hip_bfloat16*)(wsf + 4313600);     // 20,480 bf16
  __hip_bfloat16* oWp  = (__hip_bfloat16*)(wsf + 4323840);     // 8,192 bf16
  __hip_bfloat16* xpad = (__hip_bfloat16*)(wsf + 4327936);     // 5,030,912 bf16
  __hip_bfloat16* lnx  = xpad;                                 // alias (post-conv)
  __hip_bfloat16* Lbuf = (__hip_bfloat16*)(wsf + 6843392);     // 8,388,608 bf16
  __hip_bfloat16* Gbuf = (__hip_bfloat16*)(wsf + 11037696);    // 8,388,608 bf16
  __hip_bfloat16* dbc  = (__hip_bfloat16*)(wsf + 15232000);    // 10,485,760 bf16
  __hip_bfloat16* Yacc = (__hip_bfloat16*)(wsf + 20474880);    // 8,388,608 bf16
  __hip_bfloat16* xl   = (__hip_bfloat16*)buf1;                // alias (x1 dead after apply_ln)

  setup_k<<<3497, 256, 0, stream>>>((uint4*)xpad, cr1w, cr2w, left_w, rw, dw, bpw, cpw, ow,
                                    alog, W4a, W4b, Wlr, Wdbc, oWp, negA2);

  // conv-res block 1
  pack_k<<<2048, 256, 0, stream>>>(x, xpad);
  conv_mfma_k<<<512, 256, 0, stream>>>(xpad, W4a, out);
  inorm_stats_k<<<128, 256, 0, stream>>>(out, stats);
  apply_pack_k<<<2048, 256, 0, stream>>>(x, out, stats, buf1, xpad);
  // conv-res block 2 (fused apply + LayerNorm; x2 never materialized)
  conv_mfma_k<<<512, 256, 0, stream>>>(xpad, W4b, out);
  inorm_stats_k<<<128, 256, 0, stream>>>(out, stats);
  apply_ln_k<<<2048, 256, 0, stream>>>(buf1, out, stats, ln_w, ln_b, lnx);

  // mamba: axis-independent projection once
  gemm_lr_k<<<1024, 256, 0, stream>>>(lnx, Wlr, Lbuf, Gbuf);

  // per-axis: dbc_k -> scan_k (accumulates wax-weighted Y into Yacc)
  const int sh[3] = {10, 5, 0};
  for (int axis = 0; axis < 3; axis++){
    dbc_k<<<1024, 256, 0, stream>>>(Lbuf, c1dw, c1db, Wdbc, db, xl, dbc, sh[axis]);
    scan_k<<<1024, 256, 0, stream>>>(dbc, xl, Gbuf, negA2, pnw, pnb, axw, Yacc,
                                     axis, axis == 0 ? 1 : 0);
  }
  // single out-projection + residual finalize
  gemm_out_k<<<1024, 256, 0, stream>>>(Yacc, oWp, x, rsc, out);
}

// Round 11
// 524.481 us; speedup vs baseline: 1.0097x; 1.0097x over previous
//
#include <hip/hip_runtime.h>
#include <hip/hip_bf16.h>
#include <math.h>
#include <stdint.h>

// ---------------------------------------------------------------------------
// Full U-Mamba block. R20: dbc_k + scan_k FUSED (dbcscan_k).
//   R19 was neutral -> scan's micro-levers exhausted; the structural cost is
//   the dbc->scan HBM round-trip: 75 MB/axis (dbc 21MB w+r, xl 16.8MB w+r)
//   just to hand tiles between kernels. Fused: conv1d+silu -> LDS, GEMM
//   epilogue -> LDS (delta bf16, B/C f32), scan reads LDS; only Gb reads
//   and Yacc RMW remain global. LDS 58KB -> 2 blocks/CU; cross-block phase
//   overlap (MFMA vs trans vs VALU).
// R17/R18 wins kept: HW exp2 in scan, HW softplus in epilogue.
// ---------------------------------------------------------------------------

typedef __attribute__((ext_vector_type(8))) short short8;   // 8 bf16 = 4 VGPR
typedef __attribute__((ext_vector_type(4))) float f32x4;

__device__ __forceinline__ float siluf(float x){ return x * (1.0f / (1.0f + __expf(-x))); }
__device__ __forceinline__ float softplusf(float x){ return fmaxf(x, 0.0f) + log1pf(__expf(-fabsf(x))); }
// HW-transcendental softplus: v_exp_f32 + v_log_f32 (both ~1ulp), ~6 VALU ops.
__device__ __forceinline__ float softplus_hw(float x){
  float t = __builtin_amdgcn_exp2f(-fabsf(x) * 1.44269504088896f);
  return fmaxf(x, 0.0f) + 0.69314718055995f * __builtin_amdgcn_logf(1.0f + t);
}
__device__ __forceinline__ float b2f(short s){
  unsigned int u = ((unsigned int)(unsigned short)s) << 16;
  float f; __builtin_memcpy(&f, &u, 4); return f;
}
__device__ __forceinline__ short f2b(float v){
  __hip_bfloat16 h = __float2bfloat16(v);
  unsigned short u; __builtin_memcpy(&u, &h, 2); return (short)u;
}

// async global->LDS, 16B per lane; LDS dest is wave-uniform base + lane*16.
__device__ __forceinline__ void gld_lds16(const void* g, void* l){
  __builtin_amdgcn_global_load_lds(
      (__attribute__((address_space(1))) void*)(uintptr_t)g,
      (__attribute__((address_space(3))) void*)(uint32_t)(uintptr_t)l,
      16, 0, 0);
}

// ---------------------------------------------------------------------------
// One-shot setup: zero xpad | pack conv weights a/b -> bf16 [tap][co][ci] |
// mamba weight bf16 tables | negA2[s] = -softplus(A_log[s]) * log2(e).
// ---------------------------------------------------------------------------
__global__ __launch_bounds__(256) void setup_k(uint4* __restrict__ xz,
    const float* __restrict__ cr1w, const float* __restrict__ cr2w,
    const float* __restrict__ lw, const float* __restrict__ rwt,
    const float* __restrict__ dwt, const float* __restrict__ bw,
    const float* __restrict__ cwp, const float* __restrict__ owt,
    const float* __restrict__ alog,
    __hip_bfloat16* __restrict__ W4a, __hip_bfloat16* __restrict__ W4b,
    __hip_bfloat16* __restrict__ Wlr, __hip_bfloat16* __restrict__ Wd,
    __hip_bfloat16* __restrict__ oWp, float* __restrict__ negA2)
{
  int i = blockIdx.x * 256 + threadIdx.x;
  if (i < 628864){ uint4 z; z.x = z.y = z.z = z.w = 0u; xz[i] = z; return; }
  i -= 628864;
  if (i < 110592){
    int tap = i >> 12, co = (i >> 6) & 63, ci = i & 63;
    W4a[i] = __float2bfloat16(cr1w[(co * 64 + ci) * 27 + tap]); return;
  }
  i -= 110592;
  if (i < 110592){
    int tap = i >> 12, co = (i >> 6) & 63, ci = i & 63;
    W4b[i] = __float2bfloat16(cr2w[(co * 64 + ci) * 27 + tap]); return;
  }
  i -= 110592;
  if (i < 16384){
    int row = i >> 6, c = i & 63;
    float v = (row < 128) ? lw[row * 64 + c] : rwt[(row - 128) * 64 + c];
    Wlr[i] = __float2bfloat16(v); return;
  }
  i -= 16384;
  if (i < 20480){
    int row = i >> 7, k = i & 127;
    float v = (row < 128) ? dwt[row * 128 + k]
            : (row < 144 ? bw[(row - 128) * 128 + k] : cwp[(row - 144) * 128 + k]);
    Wd[i] = __float2bfloat16(v); return;
  }
  i -= 20480;
  if (i < 8192){ oWp[i] = __float2bfloat16(owt[i]); return; }
  i -= 8192;
  if (i < 16){ negA2[i] = -softplusf(alog[i]) * 1.44269504088896f; return; }
}

// ---------------------------------------------------------------------------
// Pack fp32 NCDHW -> padded channels-last bf16 [b][h+1][w+1][d+1][c] (conv1).
// ---------------------------------------------------------------------------
__global__ __launch_bounds__(256) void pack_k(const float* __restrict__ xin,
                                              __hip_bfloat16* __restrict__ xpad)
{
  __shared__ float lds[64 * 33];
  const int t = threadIdx.x, blk = blockIdx.x;
  const int b = blk >> 10, h = (blk >> 5) & 31, w = blk & 31;
  const size_t rbase = ((size_t)(b * 64) << 15) + h * 1024 + w * 32;
  #pragma unroll
  for (int r = 0; r < 8; r++){
    int c = r * 8 + (t >> 5), d = t & 31;
    lds[c * 33 + d] = xin[rbase + (size_t)c * 32768 + d];
  }
  __syncthreads();
  const size_t wbase = (size_t)b * 2515456 + (size_t)(h + 1) * 73984 + (w + 1) * 2176 + 64;
  #pragma unroll
  for (int r = 0; r < 8; r++){
    int d = r * 4 + (t >> 6), c = t & 63;
    xpad[wbase + d * 64 + c] = __float2bfloat16(lds[c * 33 + d]);
  }
}

// ---------------------------------------------------------------------------
// Conv3d implicit GEMM, bf16 MFMA 16x16x32, LDS-staged (m97 pattern, R8).
// ---------------------------------------------------------------------------
__global__ __launch_bounds__(256) void conv_mfma_k(const __hip_bfloat16* __restrict__ xpad,
    const __hip_bfloat16* __restrict__ W4, float* __restrict__ y)
{
  __shared__ short smem[6144];   // [0,4096): B tile; [4096,6144): A tile

  const int t = threadIdx.x;
  const int wave = t >> 6, lane = t & 63;
  const int quad = lane >> 4, ln = lane & 15;

  const int blk = blockIdx.x;          // 512 blocks
  const int xcd = blk & 7, j = blk >> 3;
  const int b = j >> 5, jj = j & 31;
  const int h = xcd * 4 + (jj >> 3);
  const int w0 = (jj & 7) * 4;

  const int bcol = (lane >> 2) * 64 + (lane & 3) * 8;
  const __hip_bfloat16* Bg = xpad + (size_t)b * 2515456 + (size_t)h * 73984
                                  + (size_t)(w0 + wave) * 2176 + bcol;
  const __hip_bfloat16* Ag = W4 + wave * 1024 + bcol;
  short* Bl0 = &smem[wave * 1024];
  short* Bl1 = &smem[wave * 1024 + 512];
  short* Al  = &smem[4096 + wave * 512];

  f32x4 acc[2][4];
  #pragma unroll
  for (int jn = 0; jn < 2; jn++)
    #pragma unroll
    for (int m = 0; m < 4; m++) acc[jn][m] = (f32x4){0.f, 0.f, 0.f, 0.f};

  const int aoff = ln * 32 + quad * 8;
  const int boff = (wave * 32 + ln) * 32 + quad * 8;

  for (int s = 0; s < 54; s++){
    const int t1 = s >> 1, ch = s & 1;
    const int ki = t1 / 9, kj = (t1 / 3) % 3, kk = t1 % 3;
    const int tapoff = ki * 73984 + kj * 2176 + kk * 64 + ch * 32;

    __syncthreads();
    gld_lds16(Bg + tapoff,        Bl0);
    gld_lds16(Bg + tapoff + 1024, Bl1);
    gld_lds16(Ag + t1 * 4096 + ch * 32, Al);
    __syncthreads();

    short8 a0 = *(const short8*)&smem[4096 + aoff];
    short8 a1 = *(const short8*)&smem[4096 + 512 + aoff];
    short8 a2 = *(const short8*)&smem[4096 + 1024 + aoff];
    short8 a3 = *(const short8*)&smem[4096 + 1536 + aoff];
    short8 b0 = *(const short8*)&smem[boff];
    short8 b1 = *(const short8*)&smem[boff + 512];

    acc[0][0] = __builtin_amdgcn_mfma_f32_16x16x32_bf16(a0, b0, acc[0][0], 0, 0, 0);
    acc[0][1] = __builtin_amdgcn_mfma_f32_16x16x32_bf16(a1, b0, acc[0][1], 0, 0, 0);
    acc[0][2] = __builtin_amdgcn_mfma_f32_16x16x32_bf16(a2, b0, acc[0][2], 0, 0, 0);
    acc[0][3] = __builtin_amdgcn_mfma_f32_16x16x32_bf16(a3, b0, acc[0][3], 0, 0, 0);
    acc[1][0] = __builtin_amdgcn_mfma_f32_16x16x32_bf16(a0, b1, acc[1][0], 0, 0, 0);
    acc[1][1] = __builtin_amdgcn_mfma_f32_16x16x32_bf16(a1, b1, acc[1][1], 0, 0, 0);
    acc[1][2] = __builtin_amdgcn_mfma_f32_16x16x32_bf16(a2, b1, acc[1][2], 0, 0, 0);
    acc[1][3] = __builtin_amdgcn_mfma_f32_16x16x32_bf16(a3, b1, acc[1][3], 0, 0, 0);
  }

  const size_t sbase = (size_t)h * 1024 + (w0 + wave) * 32 + ln;
  #pragma unroll
  for (int jn = 0; jn < 2; jn++){
    #pragma unroll
    for (int mt = 0; mt < 4; mt++){
      #pragma unroll
      for (int reg = 0; reg < 4; reg++){
        int co = mt * 16 + quad * 4 + reg;
        y[(((size_t)(b * 64 + co)) << 15) + sbase + jn * 16] = acc[jn][mt][reg];
      }
    }
  }
}

// ---------------------------------------------------------------------------
// InstanceNorm3d stats: one block per (b,c); stats[g]=mu, stats[128+g]=rsigma.
// ---------------------------------------------------------------------------
__global__ __launch_bounds__(256) void inorm_stats_k(const float* __restrict__ y,
                                                     float* __restrict__ stats)
{
  __shared__ float ss[256], ss2[256];
  const int t = threadIdx.x, g = blockIdx.x;
  const float* p = y + (size_t)g * 32768;
  float s = 0.0f, s2 = 0.0f;
  for (int i = t; i < 32768; i += 256){ float v = p[i]; s += v; s2 += v * v; }
  ss[t] = s; ss2[t] = s2;
  __syncthreads();
  for (int off = 128; off > 0; off >>= 1){
    if (t < off){ ss[t] += ss[t + off]; ss2[t] += ss2[t + off]; }
    __syncthreads();
  }
  if (t == 0){
    float mu = ss[0] * (1.0f / 32768.0f);
    float var = ss2[0] * (1.0f / 32768.0f) - mu * mu;
    stats[g] = mu;
    stats[128 + g] = rsqrtf(var + 1e-5f);
  }
}

// ---------------------------------------------------------------------------
// Fused: InstanceNorm-apply + LeakyReLU + residual -> x1 (fp32 NCDHW)
// AND bf16 channels-last re-pack into xpad (input of conv2).
// ---------------------------------------------------------------------------
__global__ __launch_bounds__(256) void apply_pack_k(const float* __restrict__ xin,
    const float* __restrict__ y, const float* __restrict__ stats,
    float* __restrict__ x1, __hip_bfloat16* __restrict__ xpad)
{
  __shared__ float lds[64 * 33];
  const int t = threadIdx.x, blk = blockIdx.x;
  const int b = blk >> 10, h = (blk >> 5) & 31, w = blk & 31;
  const size_t rbase = ((size_t)(b * 64) << 15) + h * 1024 + w * 32;
  #pragma unroll
  for (int r = 0; r < 8; r++){
    int c = r * 8 + (t >> 5), d = t & 31;
    float mu = stats[b * 64 + c], rs = stats[128 + b * 64 + c];
    float v = (y[rbase + (size_t)c * 32768 + d] - mu) * rs;
    v = (v >= 0.0f) ? v : 0.01f * v;
    v += xin[rbase + (size_t)c * 32768 + d];
    x1[rbase + (size_t)c * 32768 + d] = v;
    lds[c * 33 + d] = v;
  }
  __syncthreads();
  const size_t wbase = (size_t)b * 2515456 + (size_t)(h + 1) * 73984 + (w + 1) * 2176 + 64;
  #pragma unroll
  for (int r = 0; r < 8; r++){
    int d = r * 4 + (t >> 6), c = t & 63;
    xpad[wbase + d * 64 + c] = __float2bfloat16(lds[c * 33 + d]);
  }
}

// ---------------------------------------------------------------------------
// Fused: InstanceNorm-apply + LeakyReLU + residual + LayerNorm over C
// -> bf16 channels-last lnx [pos][64]. x2 never materialized.
// ---------------------------------------------------------------------------
__global__ __launch_bounds__(256) void apply_ln_k(const float* __restrict__ x1,
    const float* __restrict__ y, const float* __restrict__ stats,
    const float* __restrict__ lnw, const float* __restrict__ lnb,
    __hip_bfloat16* __restrict__ lnx)
{
  __shared__ float lds[64 * 33];
  __shared__ float s_mu[32], s_rs[32];
  const int t = threadIdx.x, blk = blockIdx.x;
  const int b = blk >> 10, h = (blk >> 5) & 31, w = blk & 31;
  const size_t rbase = ((size_t)(b * 64) << 15) + h * 1024 + w * 32;
  #pragma unroll
  for (int r = 0; r < 8; r++){
    int c = r * 8 + (t >> 5), d = t & 31;
    float mu = stats[b * 64 + c], rs = stats[128 + b * 64 + c];
    float v = (y[rbase + (size_t)c * 32768 + d] - mu) * rs;
    v = (v >= 0.0f) ? v : 0.01f * v;
    lds[c * 33 + d] = v + x1[rbase + (size_t)c * 32768 + d];
  }
  __syncthreads();
  if (t < 32){
    float s = 0.f, s2 = 0.f;
    for (int c = 0; c < 64; c++){ float v = lds[c * 33 + t]; s += v; s2 += v * v; }
    float mu = s * (1.f / 64.f);
    float var = s2 * (1.f / 64.f) - mu * mu;
    s_mu[t] = mu; s_rs[t] = rsqrtf(var + 1e-5f);
  }
  __syncthreads();
  const int d = t >> 3, c0 = (t & 7) * 8;
  const int pos = b * 32768 + h * 1024 + w * 32 + d;
  const float mu = s_mu[d], rs = s_rs[d];
  short8 o;
  #pragma unroll
  for (int j = 0; j < 8; j++){
    int c = c0 + j;
    o[j] = f2b((lds[c * 33 + d] - mu) * rs * lnw[c] + lnb[c]);
  }
  *(short8*)&lnx[(size_t)pos * 64 + c0] = o;
}

// ---------------------------------------------------------------------------
// GEMM [65536,64] x [64,256] -> Lbuf (cols 0-127 raw) + Gbuf (silu, 128-255).
// ---------------------------------------------------------------------------
__global__ __launch_bounds__(256) void gemm_lr_k(const __hip_bfloat16* __restrict__ lnx,
    const __hip_bfloat16* __restrict__ Wlr, __hip_bfloat16* __restrict__ Lb,
    __hip_bfloat16* __restrict__ Gb)
{
  const int t = threadIdx.x, wave = t >> 6, lane = t & 63, quad = lane >> 4, ln = lane & 15;
  const int pos0 = blockIdx.x * 64 + wave * 16;
  f32x4 acc[16];
  #pragma unroll
  for (int nt = 0; nt < 16; nt++) acc[nt] = (f32x4){0.f, 0.f, 0.f, 0.f};
  #pragma unroll
  for (int ks = 0; ks < 2; ks++){
    short8 a = *(const short8*)&lnx[(size_t)(pos0 + ln) * 64 + ks * 32 + quad * 8];
    #pragma unroll
    for (int nt = 0; nt < 16; nt++){
      short8 bv = *(const short8*)&Wlr[(nt * 16 + ln) * 64 + ks * 32 + quad * 8];
      acc[nt] = __builtin_amdgcn_mfma_f32_16x16x32_bf16(a, bv, acc[nt], 0, 0, 0);
    }
  }
  #pragma unroll
  for (int nt = 0; nt < 16; nt++){
    int col = nt * 16 + ln;
    #pragma unroll
    for (int reg = 0; reg < 4; reg++){
      int pos = pos0 + quad * 4 + reg;
      float v = acc[nt][reg];
      if (col < 128) Lb[(size_t)pos * 128 + col] = __float2bfloat16(v);
      else           Gb[(size_t)pos * 128 + col - 128] = __float2bfloat16(siluf(v));
    }
  }
}

// ---------------------------------------------------------------------------
// FUSED per-axis: conv1d(k=4)+silu -> LDS | GEMM [64,128]x[128,160] -> LDS |
// selective scan + gate + post-LN + wax-accumulate into Yacc.
// 2 sequences per 256-thread block; grid 1024. dbc/xl NEVER touch HBM.
// ---------------------------------------------------------------------------
__global__ __launch_bounds__(256) void dbcscan_k(const __hip_bfloat16* __restrict__ Lb,
    const float* __restrict__ cw, const float* __restrict__ cb,
    const __hip_bfloat16* __restrict__ Wd, const float* __restrict__ db,
    const __hip_bfloat16* __restrict__ Gb, const float* __restrict__ negA2,
    const float* __restrict__ pnw, const float* __restrict__ pnb,
    const float* __restrict__ axw, __hip_bfloat16* __restrict__ Yacc,
    int axis, int first)
{
  __shared__ short s_xl[64 * 136];           // silu(conv1d) bf16, row = sl*32+l
  __shared__ short s_d[64 * 128];            // delta bf16
  __shared__ float s_B[2][32][16];           // B f32
  __shared__ float s_C[2][32][16];           // C f32
  __shared__ unsigned short s_y[2][32][132]; // gated y bf16 (pad 132)
  __shared__ float s_stat[2][32][2];         // per-l {sum, sumsq}

  const int t = threadIdx.x;
  int sigma, sh;
  if (axis == 0){ sigma = 1024; sh = 10; }
  else if (axis == 1){ sigma = 32; sh = 5; }
  else { sigma = 1; sh = 0; }

  // bases for this block's two sequences
  int bases[2];
  #pragma unroll
  for (int s = 0; s < 2; s++){
    const int seq = blockIdx.x * 2 + s;
    const int b = seq >> 10, r1 = (seq >> 5) & 31, r0 = seq & 31;
    if (axis == 0)      bases[s] = b * 32768 + r1 * 32 + r0;
    else if (axis == 1) bases[s] = b * 32768 + r1 * 1024 + r0;
    else                bases[s] = b * 32768 + r1 * 1024 + r0 * 32;
  }

  // --- Phase A: conv1d(k=4) + silu -> s_xl --------------------------------
  {
    const int c0 = (t & 15) * 8;
    const int pibase = t >> 4;
    float4 w4[8]; float cbv[8];
    #pragma unroll
    for (int c = 0; c < 8; c++){ w4[c] = *(const float4*)&cw[(c0 + c) * 4]; cbv[c] = cb[c0 + c]; }
    #pragma unroll
    for (int r = 0; r < 4; r++){
      const int row = pibase + r * 16;          // 0..63
      const int sl_ = row >> 5, l = row & 31;
      const int pos = bases[sl_] + l * sigma;
      float acc[8];
      #pragma unroll
      for (int c = 0; c < 8; c++) acc[c] = cbv[c];
      #pragma unroll
      for (int j = 0; j < 4; j++){
        const int off = 3 - j;
        if (l >= off){
          short8 lv = *(const short8*)&Lb[(size_t)(pos - off * sigma) * 128 + c0];
          #pragma unroll
          for (int c = 0; c < 8; c++){
            float wv = (j == 0) ? w4[c].x : (j == 1) ? w4[c].y : (j == 2) ? w4[c].z : w4[c].w;
            acc[c] += wv * b2f(lv[c]);
          }
        }
      }
      short8 o;
      #pragma unroll
      for (int c = 0; c < 8; c++) o[c] = f2b(siluf(acc[c]));
      *(short8*)&s_xl[row * 136 + c0] = o;
    }
  }
  __syncthreads();

  // --- Phase B: GEMM [64,128] x [128,160]; epilogue -> s_d / s_B / s_C ----
  const int wave = t >> 6, lane = t & 63, quad = lane >> 4, ln = lane & 15;
  {
    const int rowb = (wave * 16 + ln) * 136;
    f32x4 acc2[10];
    #pragma unroll
    for (int nt = 0; nt < 10; nt++) acc2[nt] = (f32x4){0.f, 0.f, 0.f, 0.f};
    #pragma unroll
    for (int ks = 0; ks < 4; ks++){
      short8 a = *(const short8*)&s_xl[rowb + ks * 32 + quad * 8];
      #pragma unroll
      for (int nt = 0; nt < 10; nt++){
        short8 bv = *(const short8*)&Wd[(nt * 16 + ln) * 128 + ks * 32 + quad * 8];
        acc2[nt] = __builtin_amdgcn_mfma_f32_16x16x32_bf16(a, bv, acc2[nt], 0, 0, 0);
      }
    }
    const int row0 = wave * 16 + quad * 4;
    #pragma unroll
    for (int nt = 0; nt < 10; nt++){
      const int col = nt * 16 + ln;
      const bool isd = col < 128;
      const float dbv = isd ? db[col] : 0.f;
      #pragma unroll
      for (int reg = 0; reg < 4; reg++){
        const int row = row0 + reg;
        float v = acc2[nt][reg];
        if (isd){
          v = fminf(fmaxf(softplus_hw(v + dbv), 1e-4f), 10.f);
          s_d[row * 128 + col] = f2b(v);
        } else {
          const int sl_ = row >> 5, l = row & 31, cc = col - 128;
          if (cc < 16) s_B[sl_][l][cc] = v;
          else         s_C[sl_][l][cc - 16] = v;
        }
      }
    }
  }

  // scan setup (registers independent of phase B results)
  float A2[16], h[16];
  #pragma unroll
  for (int s = 0; s < 16; s++){ A2[s] = negA2[s]; h[s] = 0.f; }
  const int wv = wave;
  const int sl = wv >> 1;                    // seq_local 0/1
  const int half = wv & 1;                   // channel half 0/1
  const int ch = half * 64 + lane;
  const int base = bases[sl];
  const size_t sx = (size_t)sigma * 128;
  const __hip_bfloat16* pg = Gb + (size_t)base * 128 + ch;

  __syncthreads();

  // --- Phase C1: serial scan; dt/xt/B/C from LDS; g from global ----------
  unsigned short gu = *(const unsigned short*)pg;
  #pragma unroll
  for (int l = 0; l < 32; l++){
    unsigned short ngu = 0;
    if (l + 1 < 32) ngu = *(const unsigned short*)(pg + sx);
    const int row = sl * 32 + l;
    float dt = b2f(s_d[row * 128 + ch]);
    float xt = b2f(s_xl[row * 136 + ch]);
    float g = b2f((short)gu);
    float dx = dt * xt;
    f32x4 Bq[4], Cq[4];
    #pragma unroll
    for (int q = 0; q < 4; q++){
      Bq[q] = *(const f32x4*)&s_B[sl][l][q * 4];
      Cq[q] = *(const f32x4*)&s_C[sl][l][q * 4];
    }
    float y = 0.f;
    #pragma unroll
    for (int q = 0; q < 4; q++){
      #pragma unroll
      for (int r = 0; r < 4; r++){
        const int s = q * 4 + r;
        h[s] = __builtin_amdgcn_exp2f(dt * A2[s]) * h[s] + dx * Bq[q][r];
        y += h[s] * Cq[q][r];
      }
    }
    s_y[sl][l][ch] = (unsigned short)f2b(y * g);
    gu = ngu;
    pg += sx;
  }
  __syncthreads();

  // --- Phase C2: cooperative per-l reduction (sum, sumsq over 128 ch) ----
  {
    const int row = t >> 2, part = t & 3;    // row = sl2*32 + l2
    const int sl2 = row >> 5, l2 = row & 31;
    const unsigned short* yr = &s_y[sl2][l2][part * 32];
    float s1 = 0.f, s2 = 0.f;
    #pragma unroll
    for (int i = 0; i < 32; i++){
      float v = b2f((short)yr[i]);
      s1 += v; s2 += v * v;
    }
    s1 += __shfl_xor(s1, 1); s2 += __shfl_xor(s2, 1);
    s1 += __shfl_xor(s1, 2); s2 += __shfl_xor(s2, 2);
    if (part == 0){ s_stat[sl2][l2][0] = s1; s_stat[sl2][l2][1] = s2; }
  }
  __syncthreads();

  // --- Phase C3: LN over 128 ch + wax + Yacc accumulate ------------------
  float a0 = axw[0], a1 = axw[1], a2 = axw[2];
  float mxw = fmaxf(a0, fmaxf(a1, a2));
  float e0 = __expf(a0 - mxw), e1 = __expf(a1 - mxw), e2 = __expf(a2 - mxw);
  float wax = ((axis == 0) ? e0 : (axis == 1) ? e1 : e2) / (e0 + e1 + e2);
  const float pw = pnw[ch], pb = pnb[ch];

  __hip_bfloat16* py = Yacc + (size_t)base * 128 + ch;
  #pragma unroll
  for (int l = 0; l < 32; l++){
    float ss1 = s_stat[sl][l][0];
    float ss2 = s_stat[sl][l][1];
    float mu = ss1 * (1.f / 128.f);
    float var = ss2 * (1.f / 128.f) - mu * mu;
    float rs = rsqrtf(fmaxf(var, 0.f) + 1e-5f);
    float yv = b2f((short)s_y[sl][l][ch]);
    float o = ((yv - mu) * rs * pw + pb) * wax;
    if (!first) o += b2f((short)*(const unsigned short*)py);
    *(unsigned short*)py = (unsigned short)f2b(o);
    py += sx;
  }
}

// ---------------------------------------------------------------------------
// SINGLE out-projection GEMM (Yacc already holds sum of wax-weighted Y over
// all 3 axes) + residual finalize: out = x + rs * (Yacc @ oW^T). Coalesced.
// ---------------------------------------------------------------------------
__global__ __launch_bounds__(256) void gemm_out_k(const __hip_bfloat16* __restrict__ Yb,
    const __hip_bfloat16* __restrict__ oW, const float* __restrict__ xres,
    const float* __restrict__ rsc, float* __restrict__ outp)
{
  const int t = threadIdx.x, wave = t >> 6, lane = t & 63, quad = lane >> 4, ln = lane & 15;
  const int pos0 = blockIdx.x * 64 + wave * 16;
  f32x4 acc[4];
  #pragma unroll
  for (int mt = 0; mt < 4; mt++) acc[mt] = (f32x4){0.f, 0.f, 0.f, 0.f};
  #pragma unroll
  for (int ks = 0; ks < 4; ks++){
    short8 bv = *(const short8*)&Yb[(size_t)(pos0 + ln) * 128 + ks * 32 + quad * 8];
    #pragma unroll
    for (int mt = 0; mt < 4; mt++){
      short8 a = *(const short8*)&oW[(mt * 16 + ln) * 128 + ks * 32 + quad * 8];
      acc[mt] = __builtin_amdgcn_mfma_f32_16x16x32_bf16(a, bv, acc[mt], 0, 0, 0);
    }
  }
  float rs = rsc[0];
  const int pos = pos0 + ln;
  const int bb = pos >> 15, hwd = pos & 32767;
  #pragma unroll
  for (int mt = 0; mt < 4; mt++){
    #pragma unroll
    for (int reg = 0; reg < 4; reg++){
      int co = mt * 16 + quad * 4 + reg;
      size_t idx = (((size_t)(bb * 64 + co)) << 15) + hwd;
      outp[idx] = xres[idx] + rs * acc[mt][reg];
    }
  }
}

// ---------------------------------------------------------------------------
extern "C" void kernel_launch(void* const* d_in, const int* in_sizes, int n_in,
                              void* d_out, int out_size, void* d_ws, size_t ws_size,
                              hipStream_t stream)
{
  const float* x      = (const float*)d_in[0];
  const float* cr1w   = (const float*)d_in[1];
  const float* cr2w   = (const float*)d_in[3];
  const float* ln_w   = (const float*)d_in[5];
  const float* ln_b   = (const float*)d_in[6];
  const float* left_w = (const float*)d_in[7];
  const float* c1dw   = (const float*)d_in[8];
  const float* c1db   = (const float*)d_in[9];
  const float* dw     = (const float*)d_in[10];
  const float* db     = (const float*)d_in[11];
  const float* bpw    = (const float*)d_in[12];
  const float* cpw    = (const float*)d_in[13];
  const float* alog   = (const float*)d_in[14];
  const float* rw     = (const float*)d_in[15];
  const float* pnw    = (const float*)d_in[16];
  const float* pnb    = (const float*)d_in[17];
  const float* ow     = (const float*)d_in[18];
  const float* rsc    = (const float*)d_in[19];
  const float* axw    = (const float*)d_in[20];
  float* out = (float*)d_out;                       // conv raw out, then final out
  float* wsf = (float*)d_ws;

  float* buf1   = wsf;                                         // x1 fp32
  float* stats  = wsf + 4194304;                               // 256 f
  float* negA2  = wsf + 4194560;                               // 16 f
  __hip_bfloat16* W4a  = (__hip_bfloat16*)(wsf + 4194816);     // 110,592 bf16
  __hip_bfloat16* W4b  = W4a + 110592;
  __hip_bfloat16* Wlr  = (__hip_bfloat16*)(wsf + 4305408);     // 16,384 bf16
  __hip_bfloat16* Wdbc = (__hip_bfloat16*)(wsf + 4313600);     // 20,480 bf16
  __hip_bfloat16* oWp  = (__hip_bfloat16*)(wsf + 4323840);     // 8,192 bf16
  __hip_bfloat16* xpad = (__hip_bfloat16*)(wsf + 4327936);     // 5,030,912 bf16
  __hip_bfloat16* lnx  = xpad;                                 // alias (post-conv)
  __hip_bfloat16* Lbuf = (__hip_bfloat16*)(wsf + 6843392);     // 8,388,608 bf16
  __hip_bfloat16* Gbuf = (__hip_bfloat16*)(wsf + 11037696);    // 8,388,608 bf16
  __hip_bfloat16* Yacc = (__hip_bfloat16*)(wsf + 20474880);    // 8,388,608 bf16

  setup_k<<<3497, 256, 0, stream>>>((uint4*)xpad, cr1w, cr2w, left_w, rw, dw, bpw, cpw, ow,
                                    alog, W4a, W4b, Wlr, Wdbc, oWp, negA2);

  // conv-res block 1
  pack_k<<<2048, 256, 0, stream>>>(x, xpad);
  conv_mfma_k<<<512, 256, 0, stream>>>(xpad, W4a, out);
  inorm_stats_k<<<128, 256, 0, stream>>>(out, stats);
  apply_pack_k<<<2048, 256, 0, stream>>>(x, out, stats, buf1, xpad);
  // conv-res block 2 (fused apply + LayerNorm; x2 never materialized)
  conv_mfma_k<<<512, 256, 0, stream>>>(xpad, W4b, out);
  inorm_stats_k<<<128, 256, 0, stream>>>(out, stats);
  apply_ln_k<<<2048, 256, 0, stream>>>(buf1, out, stats, ln_w, ln_b, lnx);

  // mamba: axis-independent projection once
  gemm_lr_k<<<1024, 256, 0, stream>>>(lnx, Wlr, Lbuf, Gbuf);

  // per-axis FUSED dbc+scan (accumulates wax-weighted Y into Yacc)
  for (int axis = 0; axis < 3; axis++){
    dbcscan_k<<<1024, 256, 0, stream>>>(Lbuf, c1dw, c1db, Wdbc, db, Gbuf, negA2,
                                        pnw, pnb, axw, Yacc, axis, axis == 0 ? 1 : 0);
  }
  // single out-projection + residual finalize
  gemm_out_k<<<1024, 256, 0, stream>>>(Yacc, oWp, x, rsc, out);
}

// Round 12
// 444.648 us; speedup vs baseline: 1.1909x; 1.1795x over previous
//
#include <hip/hip_runtime.h>
#include <hip/hip_bf16.h>
#include <math.h>
#include <stdint.h>

// ---------------------------------------------------------------------------
// Full U-Mamba block. R21: dbcscan structural fixes.
//   (1) LDS alias: gated-y reuses the delta array s_d (each thread reads
//       dt[row][ch] then writes y to the same slot — per-thread same-address
//       dependence keeps order). LDS 59.4KB -> 42.5KB -> 3 blocks/CU.
//   (2) ONE launch for all 3 axes (grid 3072, axis = bid%3); per-axis output
//       buffers Y0/Y1/Y2 (no Yacc RMW, no sequential-axis dependency);
//       gemm_out accumulates via 3 MFMAs (exact: A*(B0+B1+B2)).
//   Y0/Y1/Y2 live in the dead x1 / dbc / Yacc workspace regions.
// R17/R18 wins kept: HW exp2 in scan, HW softplus in epilogue.
// ---------------------------------------------------------------------------

typedef __attribute__((ext_vector_type(8))) short short8;   // 8 bf16 = 4 VGPR
typedef __attribute__((ext_vector_type(4))) float f32x4;

__device__ __forceinline__ float siluf(float x){ return x * (1.0f / (1.0f + __expf(-x))); }
__device__ __forceinline__ float softplusf(float x){ return fmaxf(x, 0.0f) + log1pf(__expf(-fabsf(x))); }
// HW-transcendental softplus: v_exp_f32 + v_log_f32 (both ~1ulp), ~6 VALU ops.
__device__ __forceinline__ float softplus_hw(float x){
  float t = __builtin_amdgcn_exp2f(-fabsf(x) * 1.44269504088896f);
  return fmaxf(x, 0.0f) + 0.69314718055995f * __builtin_amdgcn_logf(1.0f + t);
}
__device__ __forceinline__ float b2f(short s){
  unsigned int u = ((unsigned int)(unsigned short)s) << 16;
  float f; __builtin_memcpy(&f, &u, 4); return f;
}
__device__ __forceinline__ short f2b(float v){
  __hip_bfloat16 h = __float2bfloat16(v);
  unsigned short u; __builtin_memcpy(&u, &h, 2); return (short)u;
}

// async global->LDS, 16B per lane; LDS dest is wave-uniform base + lane*16.
__device__ __forceinline__ void gld_lds16(const void* g, void* l){
  __builtin_amdgcn_global_load_lds(
      (__attribute__((address_space(1))) void*)(uintptr_t)g,
      (__attribute__((address_space(3))) void*)(uint32_t)(uintptr_t)l,
      16, 0, 0);
}

// ---------------------------------------------------------------------------
// One-shot setup: zero xpad | pack conv weights a/b -> bf16 [tap][co][ci] |
// mamba weight bf16 tables | negA2[s] = -softplus(A_log[s]) * log2(e).
// ---------------------------------------------------------------------------
__global__ __launch_bounds__(256) void setup_k(uint4* __restrict__ xz,
    const float* __restrict__ cr1w, const float* __restrict__ cr2w,
    const float* __restrict__ lw, const float* __restrict__ rwt,
    const float* __restrict__ dwt, const float* __restrict__ bw,
    const float* __restrict__ cwp, const float* __restrict__ owt,
    const float* __restrict__ alog,
    __hip_bfloat16* __restrict__ W4a, __hip_bfloat16* __restrict__ W4b,
    __hip_bfloat16* __restrict__ Wlr, __hip_bfloat16* __restrict__ Wd,
    __hip_bfloat16* __restrict__ oWp, float* __restrict__ negA2)
{
  int i = blockIdx.x * 256 + threadIdx.x;
  if (i < 628864){ uint4 z; z.x = z.y = z.z = z.w = 0u; xz[i] = z; return; }
  i -= 628864;
  if (i < 110592){
    int tap = i >> 12, co = (i >> 6) & 63, ci = i & 63;
    W4a[i] = __float2bfloat16(cr1w[(co * 64 + ci) * 27 + tap]); return;
  }
  i -= 110592;
  if (i < 110592){
    int tap = i >> 12, co = (i >> 6) & 63, ci = i & 63;
    W4b[i] = __float2bfloat16(cr2w[(co * 64 + ci) * 27 + tap]); return;
  }
  i -= 110592;
  if (i < 16384){
    int row = i >> 6, c = i & 63;
    float v = (row < 128) ? lw[row * 64 + c] : rwt[(row - 128) * 64 + c];
    Wlr[i] = __float2bfloat16(v); return;
  }
  i -= 16384;
  if (i < 20480){
    int row = i >> 7, k = i & 127;
    float v = (row < 128) ? dwt[row * 128 + k]
            : (row < 144 ? bw[(row - 128) * 128 + k] : cwp[(row - 144) * 128 + k]);
    Wd[i] = __float2bfloat16(v); return;
  }
  i -= 20480;
  if (i < 8192){ oWp[i] = __float2bfloat16(owt[i]); return; }
  i -= 8192;
  if (i < 16){ negA2[i] = -softplusf(alog[i]) * 1.44269504088896f; return; }
}

// ---------------------------------------------------------------------------
// Pack fp32 NCDHW -> padded channels-last bf16 [b][h+1][w+1][d+1][c] (conv1).
// ---------------------------------------------------------------------------
__global__ __launch_bounds__(256) void pack_k(const float* __restrict__ xin,
                                              __hip_bfloat16* __restrict__ xpad)
{
  __shared__ float lds[64 * 33];
  const int t = threadIdx.x, blk = blockIdx.x;
  const int b = blk >> 10, h = (blk >> 5) & 31, w = blk & 31;
  const size_t rbase = ((size_t)(b * 64) << 15) + h * 1024 + w * 32;
  #pragma unroll
  for (int r = 0; r < 8; r++){
    int c = r * 8 + (t >> 5), d = t & 31;
    lds[c * 33 + d] = xin[rbase + (size_t)c * 32768 + d];
  }
  __syncthreads();
  const size_t wbase = (size_t)b * 2515456 + (size_t)(h + 1) * 73984 + (w + 1) * 2176 + 64;
  #pragma unroll
  for (int r = 0; r < 8; r++){
    int d = r * 4 + (t >> 6), c = t & 63;
    xpad[wbase + d * 64 + c] = __float2bfloat16(lds[c * 33 + d]);
  }
}

// ---------------------------------------------------------------------------
// Conv3d implicit GEMM, bf16 MFMA 16x16x32, LDS-staged (m97 pattern, R8).
// ---------------------------------------------------------------------------
__global__ __launch_bounds__(256) void conv_mfma_k(const __hip_bfloat16* __restrict__ xpad,
    const __hip_bfloat16* __restrict__ W4, float* __restrict__ y)
{
  __shared__ short smem[6144];   // [0,4096): B tile; [4096,6144): A tile

  const int t = threadIdx.x;
  const int wave = t >> 6, lane = t & 63;
  const int quad = lane >> 4, ln = lane & 15;

  const int blk = blockIdx.x;          // 512 blocks
  const int xcd = blk & 7, j = blk >> 3;
  const int b = j >> 5, jj = j & 31;
  const int h = xcd * 4 + (jj >> 3);
  const int w0 = (jj & 7) * 4;

  const int bcol = (lane >> 2) * 64 + (lane & 3) * 8;
  const __hip_bfloat16* Bg = xpad + (size_t)b * 2515456 + (size_t)h * 73984
                                  + (size_t)(w0 + wave) * 2176 + bcol;
  const __hip_bfloat16* Ag = W4 + wave * 1024 + bcol;
  short* Bl0 = &smem[wave * 1024];
  short* Bl1 = &smem[wave * 1024 + 512];
  short* Al  = &smem[4096 + wave * 512];

  f32x4 acc[2][4];
  #pragma unroll
  for (int jn = 0; jn < 2; jn++)
    #pragma unroll
    for (int m = 0; m < 4; m++) acc[jn][m] = (f32x4){0.f, 0.f, 0.f, 0.f};

  const int aoff = ln * 32 + quad * 8;
  const int boff = (wave * 32 + ln) * 32 + quad * 8;

  for (int s = 0; s < 54; s++){
    const int t1 = s >> 1, ch = s & 1;
    const int ki = t1 / 9, kj = (t1 / 3) % 3, kk = t1 % 3;
    const int tapoff = ki * 73984 + kj * 2176 + kk * 64 + ch * 32;

    __syncthreads();
    gld_lds16(Bg + tapoff,        Bl0);
    gld_lds16(Bg + tapoff + 1024, Bl1);
    gld_lds16(Ag + t1 * 4096 + ch * 32, Al);
    __syncthreads();

    short8 a0 = *(const short8*)&smem[4096 + aoff];
    short8 a1 = *(const short8*)&smem[4096 + 512 + aoff];
    short8 a2 = *(const short8*)&smem[4096 + 1024 + aoff];
    short8 a3 = *(const short8*)&smem[4096 + 1536 + aoff];
    short8 b0 = *(const short8*)&smem[boff];
    short8 b1 = *(const short8*)&smem[boff + 512];

    acc[0][0] = __builtin_amdgcn_mfma_f32_16x16x32_bf16(a0, b0, acc[0][0], 0, 0, 0);
    acc[0][1] = __builtin_amdgcn_mfma_f32_16x16x32_bf16(a1, b0, acc[0][1], 0, 0, 0);
    acc[0][2] = __builtin_amdgcn_mfma_f32_16x16x32_bf16(a2, b0, acc[0][2], 0, 0, 0);
    acc[0][3] = __builtin_amdgcn_mfma_f32_16x16x32_bf16(a3, b0, acc[0][3], 0, 0, 0);
    acc[1][0] = __builtin_amdgcn_mfma_f32_16x16x32_bf16(a0, b1, acc[1][0], 0, 0, 0);
    acc[1][1] = __builtin_amdgcn_mfma_f32_16x16x32_bf16(a1, b1, acc[1][1], 0, 0, 0);
    acc[1][2] = __builtin_amdgcn_mfma_f32_16x16x32_bf16(a2, b1, acc[1][2], 0, 0, 0);
    acc[1][3] = __builtin_amdgcn_mfma_f32_16x16x32_bf16(a3, b1, acc[1][3], 0, 0, 0);
  }

  const size_t sbase = (size_t)h * 1024 + (w0 + wave) * 32 + ln;
  #pragma unroll
  for (int jn = 0; jn < 2; jn++){
    #pragma unroll
    for (int mt = 0; mt < 4; mt++){
      #pragma unroll
      for (int reg = 0; reg < 4; reg++){
        int co = mt * 16 + quad * 4 + reg;
        y[(((size_t)(b * 64 + co)) << 15) + sbase + jn * 16] = acc[jn][mt][reg];
      }
    }
  }
}

// ---------------------------------------------------------------------------
// InstanceNorm3d stats: one block per (b,c); stats[g]=mu, stats[128+g]=rsigma.
// ---------------------------------------------------------------------------
__global__ __launch_bounds__(256) void inorm_stats_k(const float* __restrict__ y,
                                                     float* __restrict__ stats)
{
  __shared__ float ss[256], ss2[256];
  const int t = threadIdx.x, g = blockIdx.x;
  const float* p = y + (size_t)g * 32768;
  float s = 0.0f, s2 = 0.0f;
  for (int i = t; i < 32768; i += 256){ float v = p[i]; s += v; s2 += v * v; }
  ss[t] = s; ss2[t] = s2;
  __syncthreads();
  for (int off = 128; off > 0; off >>= 1){
    if (t < off){ ss[t] += ss[t + off]; ss2[t] += ss2[t + off]; }
    __syncthreads();
  }
  if (t == 0){
    float mu = ss[0] * (1.0f / 32768.0f);
    float var = ss2[0] * (1.0f / 32768.0f) - mu * mu;
    stats[g] = mu;
    stats[128 + g] = rsqrtf(var + 1e-5f);
  }
}

// ---------------------------------------------------------------------------
// Fused: InstanceNorm-apply + LeakyReLU + residual -> x1 (fp32 NCDHW)
// AND bf16 channels-last re-pack into xpad (input of conv2).
// ---------------------------------------------------------------------------
__global__ __launch_bounds__(256) void apply_pack_k(const float* __restrict__ xin,
    const float* __restrict__ y, const float* __restrict__ stats,
    float* __restrict__ x1, __hip_bfloat16* __restrict__ xpad)
{
  __shared__ float lds[64 * 33];
  const int t = threadIdx.x, blk = blockIdx.x;
  const int b = blk >> 10, h = (blk >> 5) & 31, w = blk & 31;
  const size_t rbase = ((size_t)(b * 64) << 15) + h * 1024 + w * 32;
  #pragma unroll
  for (int r = 0; r < 8; r++){
    int c = r * 8 + (t >> 5), d = t & 31;
    float mu = stats[b * 64 + c], rs = stats[128 + b * 64 + c];
    float v = (y[rbase + (size_t)c * 32768 + d] - mu) * rs;
    v = (v >= 0.0f) ? v : 0.01f * v;
    v += xin[rbase + (size_t)c * 32768 + d];
    x1[rbase + (size_t)c * 32768 + d] = v;
    lds[c * 33 + d] = v;
  }
  __syncthreads();
  const size_t wbase = (size_t)b * 2515456 + (size_t)(h + 1) * 73984 + (w + 1) * 2176 + 64;
  #pragma unroll
  for (int r = 0; r < 8; r++){
    int d = r * 4 + (t >> 6), c = t & 63;
    xpad[wbase + d * 64 + c] = __float2bfloat16(lds[c * 33 + d]);
  }
}

// ---------------------------------------------------------------------------
// Fused: InstanceNorm-apply + LeakyReLU + residual + LayerNorm over C
// -> bf16 channels-last lnx [pos][64]. x2 never materialized.
// ---------------------------------------------------------------------------
__global__ __launch_bounds__(256) void apply_ln_k(const float* __restrict__ x1,
    const float* __restrict__ y, const float* __restrict__ stats,
    const float* __restrict__ lnw, const float* __restrict__ lnb,
    __hip_bfloat16* __restrict__ lnx)
{
  __shared__ float lds[64 * 33];
  __shared__ float s_mu[32], s_rs[32];
  const int t = threadIdx.x, blk = blockIdx.x;
  const int b = blk >> 10, h = (blk >> 5) & 31, w = blk & 31;
  const size_t rbase = ((size_t)(b * 64) << 15) + h * 1024 + w * 32;
  #pragma unroll
  for (int r = 0; r < 8; r++){
    int c = r * 8 + (t >> 5), d = t & 31;
    float mu = stats[b * 64 + c], rs = stats[128 + b * 64 + c];
    float v = (y[rbase + (size_t)c * 32768 + d] - mu) * rs;
    v = (v >= 0.0f) ? v : 0.01f * v;
    lds[c * 33 + d] = v + x1[rbase + (size_t)c * 32768 + d];
  }
  __syncthreads();
  if (t < 32){
    float s = 0.f, s2 = 0.f;
    for (int c = 0; c < 64; c++){ float v = lds[c * 33 + t]; s += v; s2 += v * v; }
    float mu = s * (1.f / 64.f);
    float var = s2 * (1.f / 64.f) - mu * mu;
    s_mu[t] = mu; s_rs[t] = rsqrtf(var + 1e-5f);
  }
  __syncthreads();
  const int d = t >> 3, c0 = (t & 7) * 8;
  const int pos = b * 32768 + h * 1024 + w * 32 + d;
  const float mu = s_mu[d], rs = s_rs[d];
  short8 o;
  #pragma unroll
  for (int j = 0; j < 8; j++){
    int c = c0 + j;
    o[j] = f2b((lds[c * 33 + d] - mu) * rs * lnw[c] + lnb[c]);
  }
  *(short8*)&lnx[(size_t)pos * 64 + c0] = o;
}

// ---------------------------------------------------------------------------
// GEMM [65536,64] x [64,256] -> Lbuf (cols 0-127 raw) + Gbuf (silu, 128-255).
// ---------------------------------------------------------------------------
__global__ __launch_bounds__(256) void gemm_lr_k(const __hip_bfloat16* __restrict__ lnx,
    const __hip_bfloat16* __restrict__ Wlr, __hip_bfloat16* __restrict__ Lb,
    __hip_bfloat16* __restrict__ Gb)
{
  const int t = threadIdx.x, wave = t >> 6, lane = t & 63, quad = lane >> 4, ln = lane & 15;
  const int pos0 = blockIdx.x * 64 + wave * 16;
  f32x4 acc[16];
  #pragma unroll
  for (int nt = 0; nt < 16; nt++) acc[nt] = (f32x4){0.f, 0.f, 0.f, 0.f};
  #pragma unroll
  for (int ks = 0; ks < 2; ks++){
    short8 a = *(const short8*)&lnx[(size_t)(pos0 + ln) * 64 + ks * 32 + quad * 8];
    #pragma unroll
    for (int nt = 0; nt < 16; nt++){
      short8 bv = *(const short8*)&Wlr[(nt * 16 + ln) * 64 + ks * 32 + quad * 8];
      acc[nt] = __builtin_amdgcn_mfma_f32_16x16x32_bf16(a, bv, acc[nt], 0, 0, 0);
    }
  }
  #pragma unroll
  for (int nt = 0; nt < 16; nt++){
    int col = nt * 16 + ln;
    #pragma unroll
    for (int reg = 0; reg < 4; reg++){
      int pos = pos0 + quad * 4 + reg;
      float v = acc[nt][reg];
      if (col < 128) Lb[(size_t)pos * 128 + col] = __float2bfloat16(v);
      else           Gb[(size_t)pos * 128 + col - 128] = __float2bfloat16(siluf(v));
    }
  }
}

// ---------------------------------------------------------------------------
// FUSED per-axis: conv1d(k=4)+silu -> LDS | GEMM [64,128]x[128,160] -> LDS |
// selective scan + gate + post-LN + wax-weight -> per-axis Y buffer.
// ONE launch covers all 3 axes: axis = blockIdx.x % 3, j = blockIdx.x / 3.
// Gated-y ALIASES the delta array s_d (slot dead after its dt is read).
// LDS 42.5KB -> 3 blocks/CU. dbc/xl never touch HBM; Y stores only (no RMW).
// ---------------------------------------------------------------------------
__global__ __launch_bounds__(256) void dbcscan_k(const __hip_bfloat16* __restrict__ Lb,
    const float* __restrict__ cw, const float* __restrict__ cb,
    const __hip_bfloat16* __restrict__ Wd, const float* __restrict__ db,
    const __hip_bfloat16* __restrict__ Gb, const float* __restrict__ negA2,
    const float* __restrict__ pnw, const float* __restrict__ pnb,
    const float* __restrict__ axw,
    __hip_bfloat16* __restrict__ Y0, __hip_bfloat16* __restrict__ Y1,
    __hip_bfloat16* __restrict__ Y2)
{
  __shared__ short s_xl[64 * 136];           // silu(conv1d) bf16, row = sl*32+l
  __shared__ short s_d[64 * 128];            // delta bf16; REUSED as gated-y
  __shared__ float s_B[2][32][16];           // B f32
  __shared__ float s_C[2][32][16];           // C f32
  __shared__ float s_stat[2][32][2];         // per-l {sum, sumsq}

  const int t = threadIdx.x;
  const int bid = blockIdx.x;
  const int axis = bid % 3;                  // interleave axes across dispatch
  const int j = bid / 3;                     // 0..1023 (seq pair)
  int sigma;
  if (axis == 0)      sigma = 1024;
  else if (axis == 1) sigma = 32;
  else                sigma = 1;
  __hip_bfloat16* Yax = (axis == 0) ? Y0 : (axis == 1) ? Y1 : Y2;

  // bases for this block's two sequences
  int bases[2];
  #pragma unroll
  for (int s = 0; s < 2; s++){
    const int seq = j * 2 + s;
    const int b = seq >> 10, r1 = (seq >> 5) & 31, r0 = seq & 31;
    if (axis == 0)      bases[s] = b * 32768 + r1 * 32 + r0;
    else if (axis == 1) bases[s] = b * 32768 + r1 * 1024 + r0;
    else                bases[s] = b * 32768 + r1 * 1024 + r0 * 32;
  }

  // --- Phase A: conv1d(k=4) + silu -> s_xl --------------------------------
  {
    const int c0 = (t & 15) * 8;
    const int pibase = t >> 4;
    float4 w4[8]; float cbv[8];
    #pragma unroll
    for (int c = 0; c < 8; c++){ w4[c] = *(const float4*)&cw[(c0 + c) * 4]; cbv[c] = cb[c0 + c]; }
    #pragma unroll
    for (int r = 0; r < 4; r++){
      const int row = pibase + r * 16;          // 0..63
      const int sl_ = row >> 5, l = row & 31;
      const int pos = bases[sl_] + l * sigma;
      float acc[8];
      #pragma unroll
      for (int c = 0; c < 8; c++) acc[c] = cbv[c];
      #pragma unroll
      for (int jt = 0; jt < 4; jt++){
        const int off = 3 - jt;
        if (l >= off){
          short8 lv = *(const short8*)&Lb[(size_t)(pos - off * sigma) * 128 + c0];
          #pragma unroll
          for (int c = 0; c < 8; c++){
            float wv = (jt == 0) ? w4[c].x : (jt == 1) ? w4[c].y : (jt == 2) ? w4[c].z : w4[c].w;
            acc[c] += wv * b2f(lv[c]);
          }
        }
      }
      short8 o;
      #pragma unroll
      for (int c = 0; c < 8; c++) o[c] = f2b(siluf(acc[c]));
      *(short8*)&s_xl[row * 136 + c0] = o;
    }
  }
  __syncthreads();

  // --- Phase B: GEMM [64,128] x [128,160]; epilogue -> s_d / s_B / s_C ----
  const int wave = t >> 6, lane = t & 63, quad = lane >> 4, ln = lane & 15;
  {
    const int rowb = (wave * 16 + ln) * 136;
    f32x4 acc2[10];
    #pragma unroll
    for (int nt = 0; nt < 10; nt++) acc2[nt] = (f32x4){0.f, 0.f, 0.f, 0.f};
    #pragma unroll
    for (int ks = 0; ks < 4; ks++){
      short8 a = *(const short8*)&s_xl[rowb + ks * 32 + quad * 8];
      #pragma unroll
      for (int nt = 0; nt < 10; nt++){
        short8 bv = *(const short8*)&Wd[(nt * 16 + ln) * 128 + ks * 32 + quad * 8];
        acc2[nt] = __builtin_amdgcn_mfma_f32_16x16x32_bf16(a, bv, acc2[nt], 0, 0, 0);
      }
    }
    const int row0 = wave * 16 + quad * 4;
    #pragma unroll
    for (int nt = 0; nt < 10; nt++){
      const int col = nt * 16 + ln;
      const bool isd = col < 128;
      const float dbv = isd ? db[col] : 0.f;
      #pragma unroll
      for (int reg = 0; reg < 4; reg++){
        const int row = row0 + reg;
        float v = acc2[nt][reg];
        if (isd){
          v = fminf(fmaxf(softplus_hw(v + dbv), 1e-4f), 10.f);
          s_d[row * 128 + col] = f2b(v);
        } else {
          const int sl_ = row >> 5, l = row & 31, cc = col - 128;
          if (cc < 16) s_B[sl_][l][cc] = v;
          else         s_C[sl_][l][cc - 16] = v;
        }
      }
    }
  }

  // scan setup
  float A2[16], h[16];
  #pragma unroll
  for (int s = 0; s < 16; s++){ A2[s] = negA2[s]; h[s] = 0.f; }
  const int sl = wave >> 1;                  // seq_local 0/1
  const int half = wave & 1;                 // channel half 0/1
  const int ch = half * 64 + lane;
  const int base = bases[sl];
  const size_t sx = (size_t)sigma * 128;
  const __hip_bfloat16* pg = Gb + (size_t)base * 128 + ch;

  __syncthreads();

  // --- Phase C1: serial scan; dt/xt/B/C from LDS; g from global ----------
  // dt read from s_d[row][ch], then gated-y written to the SAME slot (the
  // delta value is dead per-thread once consumed; same-address order holds).
  unsigned short gu = *(const unsigned short*)pg;
  #pragma unroll
  for (int l = 0; l < 32; l++){
    unsigned short ngu = 0;
    if (l + 1 < 32) ngu = *(const unsigned short*)(pg + sx);
    const int row = sl * 32 + l;
    float dt = b2f(s_d[row * 128 + ch]);
    float xt = b2f(s_xl[row * 136 + ch]);
    float g = b2f((short)gu);
    float dx = dt * xt;
    f32x4 Bq[4], Cq[4];
    #pragma unroll
    for (int q = 0; q < 4; q++){
      Bq[q] = *(const f32x4*)&s_B[sl][l][q * 4];
      Cq[q] = *(const f32x4*)&s_C[sl][l][q * 4];
    }
    float y = 0.f;
    #pragma unroll
    for (int q = 0; q < 4; q++){
      #pragma unroll
      for (int r = 0; r < 4; r++){
        const int s = q * 4 + r;
        h[s] = __builtin_amdgcn_exp2f(dt * A2[s]) * h[s] + dx * Bq[q][r];
        y += h[s] * Cq[q][r];
      }
    }
    s_d[row * 128 + ch] = f2b(y * g);        // alias write (gated y)
    gu = ngu;
    pg += sx;
  }
  __syncthreads();

  // --- Phase C2: cooperative per-l reduction (sum, sumsq over 128 ch) ----
  {
    const int row = t >> 2, part = t & 3;    // row = sl2*32 + l2
    const int sl2 = row >> 5, l2 = row & 31;
    const short* yr = &s_d[row * 128 + part * 32];
    float s1 = 0.f, s2 = 0.f;
    #pragma unroll
    for (int i = 0; i < 32; i++){
      float v = b2f(yr[i]);
      s1 += v; s2 += v * v;
    }
    s1 += __shfl_xor(s1, 1); s2 += __shfl_xor(s2, 1);
    s1 += __shfl_xor(s1, 2); s2 += __shfl_xor(s2, 2);
    if (part == 0){ s_stat[sl2][l2][0] = s1; s_stat[sl2][l2][1] = s2; }
  }
  __syncthreads();

  // --- Phase C3: LN over 128 ch + wax -> per-axis Y (store, no RMW) ------
  float a0 = axw[0], a1 = axw[1], a2 = axw[2];
  float mxw = fmaxf(a0, fmaxf(a1, a2));
  float e0 = __expf(a0 - mxw), e1 = __expf(a1 - mxw), e2 = __expf(a2 - mxw);
  float wax = ((axis == 0) ? e0 : (axis == 1) ? e1 : e2) / (e0 + e1 + e2);
  const float pw = pnw[ch], pb = pnb[ch];

  __hip_bfloat16* py = Yax + (size_t)base * 128 + ch;
  #pragma unroll
  for (int l = 0; l < 32; l++){
    float ss1 = s_stat[sl][l][0];
    float ss2 = s_stat[sl][l][1];
    float mu = ss1 * (1.f / 128.f);
    float var = ss2 * (1.f / 128.f) - mu * mu;
    float rs = rsqrtf(fmaxf(var, 0.f) + 1e-5f);
    float yv = b2f(s_d[(sl * 32 + l) * 128 + ch]);
    float o = ((yv - mu) * rs * pw + pb) * wax;
    *(unsigned short*)py = (unsigned short)f2b(o);
    py += sx;
  }
}

// ---------------------------------------------------------------------------
// SINGLE out-projection GEMM over Y0+Y1+Y2 (MFMA is linear in B: three
// accumulating MFMAs sum the axes exactly) + residual finalize.
// ---------------------------------------------------------------------------
__global__ __launch_bounds__(256) void gemm_out_k(const __hip_bfloat16* __restrict__ Y0,
    const __hip_bfloat16* __restrict__ Y1, const __hip_bfloat16* __restrict__ Y2,
    const __hip_bfloat16* __restrict__ oW, const float* __restrict__ xres,
    const float* __restrict__ rsc, float* __restrict__ outp)
{
  const int t = threadIdx.x, wave = t >> 6, lane = t & 63, quad = lane >> 4, ln = lane & 15;
  const int pos0 = blockIdx.x * 64 + wave * 16;
  f32x4 acc[4];
  #pragma unroll
  for (int mt = 0; mt < 4; mt++) acc[mt] = (f32x4){0.f, 0.f, 0.f, 0.f};
  #pragma unroll
  for (int ks = 0; ks < 4; ks++){
    const size_t boffs = (size_t)(pos0 + ln) * 128 + ks * 32 + quad * 8;
    short8 bv0 = *(const short8*)&Y0[boffs];
    short8 bv1 = *(const short8*)&Y1[boffs];
    short8 bv2 = *(const short8*)&Y2[boffs];
    #pragma unroll
    for (int mt = 0; mt < 4; mt++){
      short8 a = *(const short8*)&oW[(mt * 16 + ln) * 128 + ks * 32 + quad * 8];
      acc[mt] = __builtin_amdgcn_mfma_f32_16x16x32_bf16(a, bv0, acc[mt], 0, 0, 0);
      acc[mt] = __builtin_amdgcn_mfma_f32_16x16x32_bf16(a, bv1, acc[mt], 0, 0, 0);
      acc[mt] = __builtin_amdgcn_mfma_f32_16x16x32_bf16(a, bv2, acc[mt], 0, 0, 0);
    }
  }
  float rs = rsc[0];
  const int pos = pos0 + ln;
  const int bb = pos >> 15, hwd = pos & 32767;
  #pragma unroll
  for (int mt = 0; mt < 4; mt++){
    #pragma unroll
    for (int reg = 0; reg < 4; reg++){
      int co = mt * 16 + quad * 4 + reg;
      size_t idx = (((size_t)(bb * 64 + co)) << 15) + hwd;
      outp[idx] = xres[idx] + rs * acc[mt][reg];
    }
  }
}

// ---------------------------------------------------------------------------
extern "C" void kernel_launch(void* const* d_in, const int* in_sizes, int n_in,
                              void* d_out, int out_size, void* d_ws, size_t ws_size,
                              hipStream_t stream)
{
  const float* x      = (const float*)d_in[0];
  const float* cr1w   = (const float*)d_in[1];
  const float* cr2w   = (const float*)d_in[3];
  const float* ln_w   = (const float*)d_in[5];
  const float* ln_b   = (const float*)d_in[6];
  const float* left_w = (const float*)d_in[7];
  const float* c1dw   = (const float*)d_in[8];
  const float* c1db   = (const float*)d_in[9];
  const float* dw     = (const float*)d_in[10];
  const float* db     = (const float*)d_in[11];
  const float* bpw    = (const float*)d_in[12];
  const float* cpw    = (const float*)d_in[13];
  const float* alog   = (const float*)d_in[14];
  const float* rw     = (const float*)d_in[15];
  const float* pnw    = (const float*)d_in[16];
  const float* pnb    = (const float*)d_in[17];
  const float* ow     = (const float*)d_in[18];
  const float* rsc    = (const float*)d_in[19];
  const float* axw    = (const float*)d_in[20];
  float* out = (float*)d_out;                       // conv raw out, then final out
  float* wsf = (float*)d_ws;

  float* buf1   = wsf;                                         // x1 fp32 (dead after apply_ln -> Y0)
  float* stats  = wsf + 4194304;                               // 256 f
  float* negA2  = wsf + 4194560;                               // 16 f
  __hip_bfloat16* W4a  = (__hip_bfloat16*)(wsf + 4194816);     // 110,592 bf16
  __hip_bfloat16* W4b  = W4a + 110592;
  __hip_bfloat16* Wlr  = (__hip_bfloat16*)(wsf + 4305408);     // 16,384 bf16
  __hip_bfloat16* Wdbc = (__hip_bfloat16*)(wsf + 4313600);     // 20,480 bf16
  __hip_bfloat16* oWp  = (__hip_bfloat16*)(wsf + 4323840);     // 8,192 bf16
  __hip_bfloat16* xpad = (__hip_bfloat16*)(wsf + 4327936);     // 5,030,912 bf16
  __hip_bfloat16* lnx  = xpad;                                 // alias (post-conv)
  __hip_bfloat16* Lbuf = (__hip_bfloat16*)(wsf + 6843392);     // 8,388,608 bf16
  __hip_bfloat16* Gbuf = (__hip_bfloat16*)(wsf + 11037696);    // 8,388,608 bf16
  __hip_bfloat16* Y0   = (__hip_bfloat16*)wsf;                 // 8,388,608 bf16 (x1 region)
  __hip_bfloat16* Y1   = (__hip_bfloat16*)(wsf + 15232000);    // 8,388,608 bf16 (old dbc)
  __hip_bfloat16* Y2   = (__hip_bfloat16*)(wsf + 20474880);    // 8,388,608 bf16 (old Yacc)

  setup_k<<<3497, 256, 0, stream>>>((uint4*)xpad, cr1w, cr2w, left_w, rw, dw, bpw, cpw, ow,
                                    alog, W4a, W4b, Wlr, Wdbc, oWp, negA2);

  // conv-res block 1
  pack_k<<<2048, 256, 0, stream>>>(x, xpad);
  conv_mfma_k<<<512, 256, 0, stream>>>(xpad, W4a, out);
  inorm_stats_k<<<128, 256, 0, stream>>>(out, stats);
  apply_pack_k<<<2048, 256, 0, stream>>>(x, out, stats, buf1, xpad);
  // conv-res block 2 (fused apply + LayerNorm; x2 never materialized)
  conv_mfma_k<<<512, 256, 0, stream>>>(xpad, W4b, out);
  inorm_stats_k<<<128, 256, 0, stream>>>(out, stats);
  apply_ln_k<<<2048, 256, 0, stream>>>(buf1, out, stats, ln_w, ln_b, lnx);

  // mamba: axis-independent projection once
  gemm_lr_k<<<1024, 256, 0, stream>>>(lnx, Wlr, Lbuf, Gbuf);

  // ALL 3 axes in one launch (axis = bid%3); per-axis Y buffers, no RMW
  dbcscan_k<<<3072, 256, 0, stream>>>(Lbuf, c1dw, c1db, Wdbc, db, Gbuf, negA2,
                                      pnw, pnb, axw, Y0, Y1, Y2);

  // single out-projection over Y0+Y1+Y2 + residual finalize
  gemm_out_k<<<1024, 256, 0, stream>>>(Y0, Y1, Y2, oWp, x, rsc, out);
}